// Round 8
// baseline (335.239 us; speedup 1.0000x reference)
//
#include <hip/hip_runtime.h>
#include <hip/hip_bf16.h>
#include <math.h>

// Problem constants
#define NN 8192
#define HH 256
#define BB 64
#define LL 128
#define SPLITK 8

typedef __attribute__((ext_vector_type(8))) short short8v;   // 8 bf16
typedef __attribute__((ext_vector_type(4))) short short4v;   // 4 bf16
typedef __attribute__((ext_vector_type(4))) float f32x4;     // MFMA acc

static __device__ inline short bf16bits(float f) {
    __hip_bfloat16 h = __float2bfloat16(f);
    return __builtin_bit_cast(short, h);
}
static __device__ inline float bits2f(short s) {
    __hip_bfloat16 h = __builtin_bit_cast(__hip_bfloat16, s);
    return __bfloat162float(h);
}
static __device__ inline short8v cvt8(float4 f0, float4 f1) {
    short8v r;
    r[0] = bf16bits(f0.x); r[1] = bf16bits(f0.y);
    r[2] = bf16bits(f0.z); r[3] = bf16bits(f0.w);
    r[4] = bf16bits(f1.x); r[5] = bf16bits(f1.y);
    r[6] = bf16bits(f1.z); r[7] = bf16bits(f1.w);
    return r;
}
// async global -> LDS, 16 B/lane, linear dest (wave-uniform base + lane*16)
static __device__ inline void glds16(const void* src, void* lds) {
    __builtin_amdgcn_global_load_lds(
        (const __attribute__((address_space(1))) void*)src,
        (__attribute__((address_space(3))) void*)lds, 16, 0, 0);
}
template<int N> static __device__ inline void vmwait() {
    if constexpr (N == 0)  asm volatile("s_waitcnt vmcnt(0)"  ::: "memory");
    else if constexpr (N == 1)  asm volatile("s_waitcnt vmcnt(1)"  ::: "memory");
    else if constexpr (N == 2)  asm volatile("s_waitcnt vmcnt(2)"  ::: "memory");
    else if constexpr (N == 3)  asm volatile("s_waitcnt vmcnt(3)"  ::: "memory");
    else if constexpr (N == 4)  asm volatile("s_waitcnt vmcnt(4)"  ::: "memory");
    else if constexpr (N == 5)  asm volatile("s_waitcnt vmcnt(5)"  ::: "memory");
    else if constexpr (N == 6)  asm volatile("s_waitcnt vmcnt(6)"  ::: "memory");
    else if constexpr (N == 7)  asm volatile("s_waitcnt vmcnt(7)"  ::: "memory");
    else if constexpr (N == 8)  asm volatile("s_waitcnt vmcnt(8)"  ::: "memory");
    else                        asm volatile("s_waitcnt vmcnt(12)" ::: "memory");
}
static __device__ inline void lgkm0_barrier() {
    asm volatile("s_waitcnt lgkmcnt(0)" ::: "memory");
    __builtin_amdgcn_s_barrier();
    __builtin_amdgcn_sched_barrier(0);
}

// Swizzle conventions:
//  SW32  (rows consumed in [*][32]-short LDS tiles): chunk k ^= (row&3)<<3
//  SW128 (rows of >=128 shorts): k ^= (row&7)<<3
//  A-f32 (layer1 LDS tile [128 rows][8 chunks of 4 f32]): chunk pos = j ^ (row&7)

// ---------------------------------------------------------------------------
// prep: emb [8192][256] f32 -> embT [256][8192] bf16 PLAIN (blocks 0..511)
//       weight packing to bf16 B^T SW32 (blocks 512..1279)
// ---------------------------------------------------------------------------
__global__ __launch_bounds__(256) void prep(
    const float* __restrict__ emb, short* __restrict__ embT,
    const float* __restrict__ Wc, short* __restrict__ Wcb,
    const float* __restrict__ W1, const float* __restrict__ W2,
    short* __restrict__ WcatT)
{
    __shared__ short tile[64][65];
    const int bid = blockIdx.x;
    const int t = threadIdx.x;
    if (bid < 512) {
        const int k0 = (bid & 127) * 64, h0 = (bid >> 7) * 64;
#pragma unroll
        for (int i = 0; i < 16; i++) {
            int idx = t + i * 256;
            int k = idx >> 6, h = idx & 63;
            tile[h][k] = bf16bits(emb[(long)(k0 + k) * 256 + h0 + h]);
        }
        __syncthreads();
#pragma unroll
        for (int i = 0; i < 16; i++) {
            int idx = t + i * 256;
            int h = idx >> 6, k = idx & 63;
            embT[(long)(h0 + h) * NN + k0 + k] = tile[h][k];   // plain
        }
    } else {
        int i = (bid - 512) * 256 + t;
        if (i < 256 * 256) {
            int n = i >> 8, c = i & 255;
            Wcb[n * 256 + (c ^ ((n & 3) << 3))] = bf16bits(Wc[i]);
        }
        if (i < 384 * 512) {
            int n = i >> 9, d = i & 511;
            float v;
            if (n < 128)      v = W1[n * 512 + d];
            else if (n < 256) v = W2[(n - 128) * 1024 + d];
            else              v = W2[(n - 256) * 1024 + 512 + d];
            WcatT[n * 512 + (d ^ ((n & 3) << 3))] = bf16bits(v);
        }
    }
}

// ---------------------------------------------------------------------------
// layer1 = A(f32) @ embT^T -> bf16 partials. BM=128, BN=256, splitK=8.
// A: glds fp32 direct to LDS (4 bufs x 16 KB, depth-2), chunk-XOR swizzle via
// pre-swizzled glds source; cvt to bf16 at fragment read. B: direct L2->regs,
// double-buffered. 8 waves (2 m x 4 n). 64 KB LDS -> 2 blocks/CU.
// ---------------------------------------------------------------------------
__global__ __launch_bounds__(512, 4) void l1_mfma(
    const float* __restrict__ A, const short* __restrict__ embT,
    short* __restrict__ Part)
{
    __shared__ float As[4][128 * 8 * 4];   // 4 x 16 KB
    const int tid = threadIdx.x;
    const int wave = tid >> 6, lane = tid & 63;
    const int wr = wave >> 2, wc = wave & 3;
    const int r16 = lane & 15, kg = lane >> 4;
    const int sk = blockIdx.x & 7, mt = blockIdx.x >> 3;   // XCD-chunked
    const int m0 = mt * 128;
    const int kbeg = sk * 1024;
    constexpr int NIT = 32;                // 1024 / 32

    f32x4 acc[4][4] = {};

#define STAGE_A(T, BUF)                                                       \
    {                                                                         \
        _Pragma("unroll")                                                     \
        for (int c = 0; c < 2; c++) {                                         \
            int slot = c * 512 + tid;                                         \
            int row_ = slot >> 3, pos_ = slot & 7;                            \
            int j_ = pos_ ^ (row_ & 7);                                       \
            glds16(A + (long)(m0 + row_) * NN + kbeg + (T) * 32 + j_ * 4,     \
                   &As[BUF][(c * 512 + wave * 64) * 4]);                      \
        }                                                                     \
    }
#define LOAD_B(T, BR)                                                         \
    {                                                                         \
        _Pragma("unroll")                                                     \
        for (int j = 0; j < 4; j++) {                                         \
            int n_ = wc * 64 + j * 16 + r16;                                  \
            BR[j] = *(const short8v*)(embT + (long)n_ * NN + kbeg +           \
                                      (T) * 32 + kg * 8);                     \
        }                                                                     \
    }

    short8v b0[4], b1[4];
    STAGE_A(0, 0);
    STAGE_A(1, 1);
    LOAD_B(0, b0);
    vmwait<6>();               // A1 glds(2) + B0(4) outstanding -> A0 done
    lgkm0_barrier();

    for (int t = 0; t < NIT; ++t) {
        short8v (&bc)[4] = (t & 1) ? b1 : b0;
        short8v (&bn)[4] = (t & 1) ? b0 : b1;
        if (t + 1 < NIT) LOAD_B(t + 1, bn);
        if (t + 2 < NIT) STAGE_A(t + 2, (t + 2) & 3);

        const int cur = t & 3;
        short8v a[4];
#pragma unroll
        for (int i = 0; i < 4; i++) {
            int row = wr * 64 + i * 16 + r16;
            int p0 = (kg * 2) ^ (row & 7), p1 = (kg * 2 + 1) ^ (row & 7);
            float4 f0 = *(const float4*)&As[cur][(row * 8 + p0) * 4];
            float4 f1 = *(const float4*)&As[cur][(row * 8 + p1) * 4];
            a[i] = cvt8(f0, f1);
        }
#pragma unroll
        for (int i = 0; i < 4; i++)
#pragma unroll
            for (int j = 0; j < 4; j++)
                acc[i][j] = __builtin_amdgcn_mfma_f32_16x16x32_bf16(
                    a[i], bc[j], acc[i][j], 0, 0, 0);

        if (t + 1 < NIT) {
            if (t + 2 < NIT) vmwait<6>();   // B(t+1)4 + A(t+2)2 stay in flight
            else             vmwait<4>();   // only B(t+1)
            lgkm0_barrier();
        }
    }
#undef STAGE_A
#undef LOAD_B

    short* P = Part + (long)sk * NN * HH;
#pragma unroll
    for (int i = 0; i < 4; i++)
#pragma unroll
        for (int j = 0; j < 4; j++) {
            int col = wc * 64 + j * 16 + r16;
#pragma unroll
            for (int r = 0; r < 4; r++) {
                int row = m0 + wr * 64 + i * 16 + kg * 4 + r;
                P[(long)row * HH + col] = bf16bits(acc[i][j][r]);
            }
        }
}

// ---------------------------------------------------------------------------
// layer1 partial reduce (bf16 partials) -> bf16
// ---------------------------------------------------------------------------
__global__ __launch_bounds__(256) void reduceK(
    const short* __restrict__ P, short* __restrict__ out)
{
    const long n = (long)NN * HH;
    long i = ((long)blockIdx.x * 256 + threadIdx.x) * 8;
    if (i >= n) return;
    float acc[8] = {};
#pragma unroll
    for (int k = 0; k < SPLITK; k++) {
        short8v v = *(const short8v*)&P[(long)k * n + i];
#pragma unroll
        for (int j = 0; j < 8; j++) acc[j] += bits2f(v[j]);
    }
    short8v o;
#pragma unroll
    for (int j = 0; j < 8; j++) o[j] = bf16bits(acc[j]);
    *(short8v*)&out[i] = o;
}

// ---------------------------------------------------------------------------
// Small bf16 GEMM template, merged q/a sides + N-tiling for occupancy.
// BM=64, BN=NW*4, 256 threads, depth-3 (4-buffer) pipeline, counted vmcnt.
// A: bf16 [M][Kd] (optional gather). B: bf16 B^T [N][Kd] SW32 pre-swizzled.
// EPI: 1 = gram (bias+relu -> Xbf16 SW128 + per-batch XT SW128),
//      2 = plain f32 C (encoder).
// grid = (M/64) * NT * 2;  side = bid&1, nt = (bid>>1)&(NT-1), mt = bid>>(1+log2NT)
// ---------------------------------------------------------------------------
template<int NW, int NT, int GATHER, int EPI>
__global__ __launch_bounds__(256) void gemm_small(
    const short* __restrict__ Aq, const short* __restrict__ Aa,
    const short* __restrict__ Bt,
    float* __restrict__ Cfq, float* __restrict__ Cfa,
    short* __restrict__ Cbq, short* __restrict__ Cba,
    short* __restrict__ Ctq, short* __restrict__ Cta,
    const float* __restrict__ bias,
    const int* __restrict__ idxq, const int* __restrict__ idxa,
    int M, int N, int Kd)
{
    constexpr int BM = 64;
    constexpr int BN = NW * 4;
    constexpr int NB = NW / 16;
    constexpr int BCALLS = BN / BM;      // glds per B stage
    constexpr int OPS = 1 + BCALLS;      // vmem ops per stage (A reg-load + B)
    constexpr int AST = 40;

    __shared__ short As[4][BM * AST];
    __shared__ short Bs[4][BN * 32];

    const int tid = threadIdx.x;
    const int wave = tid >> 6, lane = tid & 63;
    const int wc = wave & 3;
    const int r16 = lane & 15, kg = lane >> 4;

    const int bid = blockIdx.x;
    const int side = bid & 1;
    const int nt = (bid >> 1) & (NT - 1);
    const int mt = bid >> (NT == 2 ? 2 : 1);
    const int m0 = mt * BM;
    const int n0 = nt * BN;
    const int niter = Kd / 32;

    const short* Ab = side ? Aa : Aq;
    const int* rowidx = side ? idxa : idxq;

    const int arow = tid >> 2;
    const int akc = (tid & 3) * 8;
    long arow_g;
    { int r = GATHER ? rowidx[m0 + arow] : (m0 + arow); arow_g = (long)r * Kd; }

    f32x4 acc[4][NB] = {};

#define STAGE_B(T, BUF)                                                        \
    {                                                                          \
        const int kt_ = (T) * 32;                                              \
        _Pragma("unroll")                                                      \
        for (int c = 0; c < BCALLS; c++) {                                     \
            int chunk = c * 256 + tid;                                         \
            int n_ = chunk >> 2, kc_ = (chunk & 3) * 8;                        \
            glds16(Bt + (long)(n0 + n_) * Kd + kt_ + kc_,                      \
                   &Bs[BUF][(c * 256 + wave * 64) * 8]);                       \
        }                                                                      \
    }
#define LOAD_A(T, AR)  { (AR) = *(const short8v*)(Ab + arow_g + (T) * 32 + akc); }
#define WRITE_A(BUF, AR) { *(short8v*)&As[BUF][arow * AST + akc] = (AR); }

    // prologue: tiles 0,1,2 (depth-3)
    short8v a0, a1, a2;
    LOAD_A(0, a0);  STAGE_B(0, 0);
    LOAD_A(1, a1);  STAGE_B(1, 1);
    LOAD_A(2, a2);  STAGE_B(2, 2);
    WRITE_A(0, a0);
    vmwait<2 * OPS>();
    lgkm0_barrier();

    for (int t = 0; t < niter; ++t) {
        const int cur = t & 3, nw = (t + 1) & 3, ns = (t + 3) & 3;
        short8v na;
        if (t + 3 < niter) {
            LOAD_A(t + 3, na);
            STAGE_B(t + 3, ns);
        }

        short8v a[4], b[NB];
#pragma unroll
        for (int i = 0; i < 4; i++)
            a[i] = *(const short8v*)&As[cur][(i * 16 + r16) * AST + kg * 8];
#pragma unroll
        for (int j = 0; j < NB; j++) {
            int n = wc * NW + j * 16 + r16;
            b[j] = *(const short8v*)&Bs[cur][n * 32 + ((kg * 8) ^ ((n & 3) << 3))];
        }
#pragma unroll
        for (int i = 0; i < 4; i++)
#pragma unroll
            for (int j = 0; j < NB; j++)
                acc[i][j] = __builtin_amdgcn_mfma_f32_16x16x32_bf16(
                    a[i], b[j], acc[i][j], 0, 0, 0);

        if (t + 1 < niter) {
            WRITE_A(nw, a1);
            if (t + 3 < niter)      vmwait<2 * OPS>();
            else if (t + 2 < niter) vmwait<OPS>();
            else                    vmwait<0>();
            lgkm0_barrier();
        }
        a1 = a2; a2 = na;
    }
#undef STAGE_B
#undef LOAD_A
#undef WRITE_A

    if (EPI == 2) {
        float* Cf = side ? Cfa : Cfq;
#pragma unroll
        for (int i = 0; i < 4; i++)
#pragma unroll
            for (int j = 0; j < NB; j++) {
                int col = n0 + wc * NW + j * 16 + r16;
#pragma unroll
                for (int r = 0; r < 4; r++) {
                    int row = m0 + i * 16 + kg * 4 + r;
                    Cf[(long)row * N + col] = acc[i][j][r];
                }
            }
    } else {   // EPI == 1: gram
        short* Cb = side ? Cba : Cbq;
        short* Ct = side ? Cta : Ctq;
#pragma unroll
        for (int i = 0; i < 4; i++)
#pragma unroll
            for (int j = 0; j < NB; j++) {
                int col = n0 + wc * NW + j * 16 + r16;
                float bv = bias[col];
                float vr[4];
#pragma unroll
                for (int r = 0; r < 4; r++)
                    vr[r] = fmaxf(acc[i][j][r] + bv, 0.f);
                int rbase = m0 + i * 16 + kg * 4;
                int bb = rbase >> 7;
                int lbase = rbase & 127;
#pragma unroll
                for (int r = 0; r < 4; r++) {
                    int grow = rbase + r;
                    Cb[(long)grow * 256 + (col ^ ((grow & 7) << 3))] = bf16bits(vr[r]);
                }
                short4v t4;
#pragma unroll
                for (int r = 0; r < 4; r++) t4[r] = bf16bits(vr[r]);
                int lsw = lbase ^ ((col & 7) << 3);
                *(short4v*)&Ct[(long)bb * (256 * 128) + col * 128 + lsw] = t4;
            }
    }
}

// ---------------------------------------------------------------------------
// qkT: per batch b, s[q][k] = Qm[b,q,:] . Am[b,k,:]  (bf16 MFMA, f32 out)
// ---------------------------------------------------------------------------
__global__ __launch_bounds__(256) void qkT(
    const short* __restrict__ Qb16, const short* __restrict__ Ab16,
    float* __restrict__ s)
{
    __shared__ short Q[128 * 256];
    __shared__ short Am[128 * 256];
    const int b = blockIdx.x;
    const int tid = threadIdx.x, wave = tid >> 6, lane = tid & 63;
    const int r16 = lane & 15, kg = lane >> 4;
    const long boff = (long)b * 128 * 256;

#pragma unroll
    for (int c = 0; c < 16; c++) {
        glds16(Qb16 + boff + ((long)c * 256 + tid) * 8, &Q[(c * 256 + wave * 64) * 8]);
        glds16(Ab16 + boff + ((long)c * 256 + tid) * 8, &Am[(c * 256 + wave * 64) * 8]);
    }
    __syncthreads();

    f32x4 acc[2][8] = {};
    const int q0 = wave * 32;
#pragma unroll
    for (int ks = 0; ks < 8; ks++) {
        short8v a[2], bf[8];
#pragma unroll
        for (int i = 0; i < 2; i++) {
            int q = q0 + i * 16 + r16;
            a[i] = *(const short8v*)&Q[q * 256 + ((ks * 32 + kg * 8) ^ ((q & 7) << 3))];
        }
#pragma unroll
        for (int j = 0; j < 8; j++) {
            int n = j * 16 + r16;
            bf[j] = *(const short8v*)&Am[n * 256 + ((ks * 32 + kg * 8) ^ ((n & 7) << 3))];
        }
#pragma unroll
        for (int i = 0; i < 2; i++)
#pragma unroll
            for (int j = 0; j < 8; j++)
                acc[i][j] = __builtin_amdgcn_mfma_f32_16x16x32_bf16(
                    a[i], bf[j], acc[i][j], 0, 0, 0);
    }

    float* sp = s + (long)b * 16384;
#pragma unroll
    for (int i = 0; i < 2; i++)
#pragma unroll
        for (int j = 0; j < 8; j++)
#pragma unroll
            for (int r = 0; r < 4; r++) {
                int q = q0 + i * 16 + kg * 4 + r;
                int k = j * 16 + r16;
                sp[q * 128 + k] = acc[i][j][r];
            }
}

// ---------------------------------------------------------------------------
// attn_pv merged (runtime side): softmax of s rows (side 0) / cols (side 1)
// -> P, E = P @ XT^T, fused t-features written bf16. grid = 128 (b, side).
// ---------------------------------------------------------------------------
__global__ __launch_bounds__(256) void attn_pv(
    const float* __restrict__ s,
    const short* __restrict__ AT, const short* __restrict__ QT,
    const short* __restrict__ Qb16, const short* __restrict__ Ab16,
    short* __restrict__ t_q, short* __restrict__ t_a)
{
    __shared__ float sm[128 * 128];   // 64 KB; reused for XT after softmax
    __shared__ short P[128 * 128];    // 32 KB
    short* XL = (short*)sm;
    const int b = blockIdx.x >> 1;
    const int side = blockIdx.x & 1;
    const int tid = threadIdx.x, wave = tid >> 6, lane = tid & 63;
    const int r16 = lane & 15, kg = lane >> 4;

    const short* XT   = side ? QT : AT;
    const short* Xrow = side ? Ab16 : Qb16;
    short* tout       = side ? t_a : t_q;

#pragma unroll
    for (int c = 0; c < 16; c++)
        glds16(s + (long)b * 16384 + ((long)c * 256 + tid) * 4,
               &sm[(c * 256 + wave * 64) * 4]);
    __syncthreads();

    {   // 2 threads per row, __shfl_xor(1) combine
        const int r = tid >> 1;
        const int base = (tid & 1) * 64;
        float mx = -1e30f;
#pragma unroll 8
        for (int i = 0; i < 64; i++) {
            int k = base + ((i + r) & 63);
            float v = side ? sm[k * 128 + r] : sm[r * 128 + k];
            mx = fmaxf(mx, v);
        }
        mx = fmaxf(mx, __shfl_xor(mx, 1));
        float sum = 0.f;
#pragma unroll 8
        for (int i = 0; i < 64; i++) {
            int k = base + ((i + r) & 63);
            float v = side ? sm[k * 128 + r] : sm[r * 128 + k];
            sum += __expf(v - mx);
        }
        sum += __shfl_xor(sum, 1);
        float inv = 1.f / sum;
#pragma unroll 8
        for (int i = 0; i < 64; i++) {
            int k = base + ((i + r) & 63);
            float v = side ? sm[k * 128 + r] : sm[r * 128 + k];
            P[r * 128 + (k ^ ((r & 7) << 3))] = bf16bits(__expf(v - mx) * inv);
        }
    }
    __syncthreads();

    // stage XT (overwrites sm)
#pragma unroll
    for (int c = 0; c < 16; c++)
        glds16(XT + (long)b * 32768 + ((long)c * 256 + tid) * 8,
               &XL[(c * 256 + wave * 64) * 8]);
    __syncthreads();

    f32x4 acc[8][4] = {};
#pragma unroll
    for (int ks = 0; ks < 4; ks++) {
        short8v a[8], bf[4];
#pragma unroll
        for (int i = 0; i < 8; i++) {
            int row = i * 16 + r16;
            a[i] = *(const short8v*)&P[row * 128 + ((ks * 32 + kg * 8) ^ ((row & 7) << 3))];
        }
#pragma unroll
        for (int j = 0; j < 4; j++) {
            int h = wave * 64 + j * 16 + r16;
            bf[j] = *(const short8v*)&XL[h * 128 + ((ks * 32 + kg * 8) ^ ((h & 7) << 3))];
        }
#pragma unroll
        for (int i = 0; i < 8; i++)
#pragma unroll
            for (int j = 0; j < 4; j++)
                acc[i][j] = __builtin_amdgcn_mfma_f32_16x16x32_bf16(
                    a[i], bf[j], acc[i][j], 0, 0, 0);
    }

    short* tp = tout + (long)b * 128 * 512;
    const short* xr = Xrow + (long)b * 128 * 256;
#pragma unroll
    for (int i = 0; i < 8; i++)
#pragma unroll
        for (int j = 0; j < 4; j++) {
            int col = wave * 64 + j * 16 + r16;
#pragma unroll
            for (int r = 0; r < 4; r++) {
                int row = i * 16 + kg * 4 + r;
                float E = acc[i][j][r];
                float x = bits2f(xr[row * 256 + (col ^ ((row & 7) << 3))]);
                float d = x - E;
                tp[(long)row * 512 + col] = bf16bits(d * d);
                tp[(long)row * 512 + 256 + col] = bf16bits(x * E);
            }
        }
}

// ---------------------------------------------------------------------------
// pool + final fused: re in LDS, then log_softmax(re @ Wd^T + bd)
// ---------------------------------------------------------------------------
__global__ __launch_bounds__(256) void pool_final(
    const float* __restrict__ u_q, const float* __restrict__ u_a,
    const float* __restrict__ b1, const float* __restrict__ b2,
    const float* __restrict__ Wd, const float* __restrict__ bd,
    float* __restrict__ out)
{
    __shared__ float re[512];
    const int b = blockIdx.x;
    const int t = threadIdx.x;
#pragma unroll
    for (int side = 0; side < 2; side++) {
        const float* uu = side ? u_a : u_q;
        if (t < 128) {
            int k = t;
            float bias = b1[k];
            float mx = -1e30f;
            for (int l = 0; l < 128; l++) {
                float v = uu[((long)b * 128 + l) * 384 + k] + bias;
                mx = fmaxf(mx, v);
            }
            re[side * 256 + k] = fmaxf(mx, 0.f);
        } else {
            int k = t - 128;
            float bias = b2[k];
            float mx = -1e30f;
            for (int l = 0; l < 127; l++) {
                float v = uu[((long)b * 128 + l) * 384 + 128 + k]
                        + uu[((long)b * 128 + l + 1) * 384 + 256 + k] + bias;
                mx = fmaxf(mx, v);
            }
            re[side * 256 + 128 + k] = fmaxf(mx, 0.f);
        }
    }
    __syncthreads();
    if (t < 64) {
        float p0 = 0.f, p1 = 0.f;
        for (int d = t; d < 512; d += 64) {
            float r = re[d];
            p0 = fmaf(r, Wd[d], p0);
            p1 = fmaf(r, Wd[512 + d], p1);
        }
#pragma unroll
        for (int off = 32; off; off >>= 1) {
            p0 += __shfl_xor(p0, off);
            p1 += __shfl_xor(p1, off);
        }
        if (t == 0) {
            float l0 = p0 + bd[0], l1 = p1 + bd[1];
            float m = fmaxf(l0, l1);
            float lse = m + logf(expf(l0 - m) + expf(l1 - m));
            out[b * 2 + 0] = l0 - lse;
            out[b * 2 + 1] = l1 - lse;
        }
    }
}

// ---------------------------------------------------------------------------
extern "C" void kernel_launch(void* const* d_in, const int* in_sizes, int n_in,
                              void* d_out, int out_size, void* d_ws, size_t ws_size,
                              hipStream_t stream)
{
    const float* A    = (const float*)d_in[0];
    const float* emb  = (const float*)d_in[1];
    const float* Wc   = (const float*)d_in[2];
    const float* bc   = (const float*)d_in[3];
    const float* W1   = (const float*)d_in[4];
    const float* b1   = (const float*)d_in[5];
    const float* W2   = (const float*)d_in[6];
    const float* b2   = (const float*)d_in[7];
    const float* Wd   = (const float*)d_in[8];
    const float* bd   = (const float*)d_in[9];
    const int* q_idx  = (const int*)d_in[10];
    const int* a_idx  = (const int*)d_in[11];
    float* out = (float*)d_out;
    float* ws  = (float*)d_ws;

    // workspace layout (float units)
    const long SZ_L1 = (long)NN * HH;                 // 2,097,152
    float* p      = ws;
    short* Part   = (short*)p;          p += (long)SPLITK * SZ_L1 / 2;  // bf16
    short* l1b    = (short*)p;          p += SZ_L1 / 2 + 1024;   // bf16 [8192][256]
    short* Wcb    = (short*)p;          p += 32768 + 1024;       // bf16 [256][256] SW32
    short* WcatT  = (short*)p;          p += 98304 + 1024;       // bf16 [384][512] SW32
    short* embT   = (short*)p;          p += SZ_L1 / 2 + 1024;   // bf16 [256][8192] plain
    short* Qb16   = (short*)p;          p += SZ_L1 / 2 + 1024;   // bf16 [8192][256] SW128
    short* Ab16   = (short*)p;          p += SZ_L1 / 2 + 1024;
    short* QT     = (short*)p;          p += SZ_L1 / 2 + 1024;   // bf16 [64][256][128] SW128
    short* AT     = (short*)p;          p += SZ_L1 / 2 + 1024;
    float* s      = p;                  p += (long)BB * LL * LL; // f32 [64][128][128]
    short* t_q    = (short*)p;          p += SZ_L1 + 1024;       // bf16 [8192][512]
    short* t_a    = (short*)p;          p += SZ_L1 + 1024;
    float* u_q    = p;                  p += (long)BB * LL * 384;
    float* u_a    = p;                  p += (long)BB * LL * 384;

    // 1. weight packing + emb transpose
    prep<<<1280, 256, 0, stream>>>(emb, embT, Wc, Wcb, W1, W2, WcatT);

    // 2. layer1: A(f32) glds + B-in-regs, splitK=8, 512 blocks, 2/CU
    l1_mfma<<<512, 512, 0, stream>>>(A, embT, Part);
    reduceK<<<(int)(SZ_L1 / 8 / 256), 256, 0, stream>>>(Part, l1b);

    // 3. gram merged q+a: BN=128 x 2 n-tiles x 2 sides = 512 blocks
    gemm_small<32, 2, 1, 1><<<512, 256, 0, stream>>>(
        l1b, l1b, Wcb, nullptr, nullptr, Qb16, Ab16, QT, AT, bc,
        q_idx, a_idx, BB * LL, HH, HH);

    // 4. attention
    qkT<<<BB, 256, 0, stream>>>(Qb16, Ab16, s);
    attn_pv<<<2 * BB, 256, 0, stream>>>(s, AT, QT, Qb16, Ab16, t_q, t_a);

    // 5. encoder merged q+a: BN=192 x 2 n-tiles x 2 sides = 512 blocks
    gemm_small<48, 2, 0, 2><<<512, 256, 0, stream>>>(
        t_q, t_a, WcatT, u_q, u_a, nullptr, nullptr, nullptr, nullptr, nullptr,
        nullptr, nullptr, BB * LL, 384, 512);

    // 6. pool + final
    pool_final<<<BB, 256, 0, stream>>>(u_q, u_a, b1, b2, Wd, bd, out);
}

// Round 9
// 227.340 us; speedup vs baseline: 1.4746x; 1.4746x over previous
//
#include <hip/hip_runtime.h>
#include <hip/hip_bf16.h>
#include <math.h>

// Problem constants
#define NN 8192
#define HH 256
#define BB 64
#define LL 128
#define SPLITK 8

typedef __attribute__((ext_vector_type(8))) short short8v;   // 8 bf16
typedef __attribute__((ext_vector_type(4))) short short4v;   // 4 bf16
typedef __attribute__((ext_vector_type(4))) float f32x4;     // MFMA acc

static __device__ inline short bf16bits(float f) {
    __hip_bfloat16 h = __float2bfloat16(f);
    return __builtin_bit_cast(short, h);
}
static __device__ inline float bits2f(short s) {
    __hip_bfloat16 h = __builtin_bit_cast(__hip_bfloat16, s);
    return __bfloat162float(h);
}
static __device__ inline short8v cvt8(float4 f0, float4 f1) {
    short8v r;
    r[0] = bf16bits(f0.x); r[1] = bf16bits(f0.y);
    r[2] = bf16bits(f0.z); r[3] = bf16bits(f0.w);
    r[4] = bf16bits(f1.x); r[5] = bf16bits(f1.y);
    r[6] = bf16bits(f1.z); r[7] = bf16bits(f1.w);
    return r;
}
// async global -> LDS, 16 B/lane, linear dest (wave-uniform base + lane*16)
static __device__ inline void glds16(const void* src, void* lds) {
    __builtin_amdgcn_global_load_lds(
        (const __attribute__((address_space(1))) void*)src,
        (__attribute__((address_space(3))) void*)lds, 16, 0, 0);
}
template<int N> static __device__ inline void vmwait() {
    if constexpr (N == 0)  asm volatile("s_waitcnt vmcnt(0)"  ::: "memory");
    else if constexpr (N == 1)  asm volatile("s_waitcnt vmcnt(1)"  ::: "memory");
    else if constexpr (N == 2)  asm volatile("s_waitcnt vmcnt(2)"  ::: "memory");
    else if constexpr (N == 3)  asm volatile("s_waitcnt vmcnt(3)"  ::: "memory");
    else if constexpr (N == 4)  asm volatile("s_waitcnt vmcnt(4)"  ::: "memory");
    else if constexpr (N == 5)  asm volatile("s_waitcnt vmcnt(5)"  ::: "memory");
    else if constexpr (N == 6)  asm volatile("s_waitcnt vmcnt(6)"  ::: "memory");
    else if constexpr (N == 7)  asm volatile("s_waitcnt vmcnt(7)"  ::: "memory");
    else if constexpr (N == 8)  asm volatile("s_waitcnt vmcnt(8)"  ::: "memory");
    else                        asm volatile("s_waitcnt vmcnt(12)" ::: "memory");
}
static __device__ inline void lgkm0_barrier() {
    asm volatile("s_waitcnt lgkmcnt(0)" ::: "memory");
    __builtin_amdgcn_s_barrier();
    __builtin_amdgcn_sched_barrier(0);
}

// Swizzle conventions:
//  SW32  (rows consumed in [*][32]-short LDS tiles): chunk k ^= (row&3)<<3
//  SW128 (rows of >=128 shorts): k ^= (row&7)<<3

// ---------------------------------------------------------------------------
// prep: emb [8192][256] f32 -> embT [256][8192] bf16 SW32 (blocks 0..511)
//       weight packing to bf16 B^T SW32 (blocks 512..1279)
// ---------------------------------------------------------------------------
__global__ __launch_bounds__(256) void prep(
    const float* __restrict__ emb, short* __restrict__ embT,
    const float* __restrict__ Wc, short* __restrict__ Wcb,
    const float* __restrict__ W1, const float* __restrict__ W2,
    short* __restrict__ WcatT)
{
    __shared__ short tile[64][65];
    const int bid = blockIdx.x;
    const int t = threadIdx.x;
    if (bid < 512) {
        const int k0 = (bid & 127) * 64, h0 = (bid >> 7) * 64;
#pragma unroll
        for (int i = 0; i < 16; i++) {
            int idx = t + i * 256;
            int k = idx >> 6, h = idx & 63;
            tile[h][k] = bf16bits(emb[(long)(k0 + k) * 256 + h0 + h]);
        }
        __syncthreads();
#pragma unroll
        for (int i = 0; i < 16; i++) {
            int idx = t + i * 256;
            int h = idx >> 6, k = idx & 63;
            int n = h0 + h;
            int kk = (k0 + k) ^ ((n & 3) << 3);   // SW32
            embT[(long)n * NN + kk] = tile[h][k];
        }
    } else {
        int i = (bid - 512) * 256 + t;
        if (i < 256 * 256) {
            int n = i >> 8, c = i & 255;
            Wcb[n * 256 + (c ^ ((n & 3) << 3))] = bf16bits(Wc[i]);
        }
        if (i < 384 * 512) {
            int n = i >> 9, d = i & 511;
            float v;
            if (n < 128)      v = W1[n * 512 + d];
            else if (n < 256) v = W2[(n - 128) * 1024 + d];
            else              v = W2[(n - 256) * 1024 + 512 + d];
            WcatT[n * 512 + (d ^ ((n & 3) << 3))] = bf16bits(v);
        }
    }
}

// ---------------------------------------------------------------------------
// layer1 = A(f32) @ embT^T -> bf16 partials. BM=128, BN=256, splitK=8.
// R7-proven structure: 4-buffer depth-3 pipeline, A f32 reg-stage + cvt into
// padded LDS, B glds SW32, counted vmcnt, raw barriers. 8 waves (2m x 4n).
// ---------------------------------------------------------------------------
__global__ __launch_bounds__(512, 2) void l1_gemm(
    const float* __restrict__ Af, const short* __restrict__ Bt,
    short* __restrict__ Part)
{
    constexpr int AST = 40;              // padded A row stride (shorts)
    constexpr int OPS = 4;               // 2 A-loads + 2 B-glds per stage

    __shared__ short As[4][128 * AST];
    __shared__ short Bs[4][256 * 32];

    const int tid = threadIdx.x;
    const int wave = tid >> 6, lane = tid & 63;
    const int wr = wave >> 2, wc = wave & 3;
    const int r16 = lane & 15, kg = lane >> 4;

    const int sk = blockIdx.x & 7, mt = blockIdx.x >> 3;   // XCD-chunked
    const int m0 = mt * 128;
    const int kbeg = sk * 1024;
    constexpr int NIT = 32;              // 1024 / 32

    const int arow = tid >> 2;
    const int akc = (tid & 3) * 8;
    const long arow_g = (long)(m0 + arow) * NN;

    f32x4 acc[4][4] = {};

#define STAGE_B(T, BUF)                                                        \
    {                                                                          \
        const int kt_ = kbeg + (T) * 32;                                       \
        _Pragma("unroll")                                                      \
        for (int c = 0; c < 2; c++) {                                          \
            int chunk = c * 512 + tid;                                         \
            int n_ = chunk >> 2, kc_ = (chunk & 3) * 8;                        \
            glds16(Bt + (long)n_ * NN + kt_ + kc_,                             \
                   &Bs[BUF][(c * 512 + wave * 64) * 8]);                       \
        }                                                                      \
    }
#define LOAD_A(T, F0, F1)                                                      \
    {                                                                          \
        const float* ap_ = Af + arow_g + kbeg + (T) * 32 + akc;                \
        (F0) = *(const float4*)ap_; (F1) = *(const float4*)(ap_ + 4);          \
    }
#define WRITE_A(BUF, F0, F1) { *(short8v*)&As[BUF][arow * AST + akc] = cvt8((F0), (F1)); }

    // prologue: tiles 0,1,2 (depth-3)
    float4 p0f0, p0f1, c1f0, c1f1, c2f0, c2f1;
    LOAD_A(0, p0f0, p0f1);  STAGE_B(0, 0);
    LOAD_A(1, c1f0, c1f1);  STAGE_B(1, 1);
    LOAD_A(2, c2f0, c2f1);  STAGE_B(2, 2);
    WRITE_A(0, p0f0, p0f1);
    vmwait<8>();            // drain tile-0 glds; tiles 1,2 stay in flight
    lgkm0_barrier();

    for (int t = 0; t < NIT; ++t) {
        const int cur = t & 3, nw = (t + 1) & 3, ns = (t + 3) & 3;
        float4 nf0, nf1;
        if (t + 3 < NIT) {
            LOAD_A(t + 3, nf0, nf1);
            STAGE_B(t + 3, ns);
        }

        short8v a[4], b[4];
#pragma unroll
        for (int i = 0; i < 4; i++)
            a[i] = *(const short8v*)&As[cur][(wr * 64 + i * 16 + r16) * AST + kg * 8];
#pragma unroll
        for (int j = 0; j < 4; j++) {
            int n = wc * 64 + j * 16 + r16;
            b[j] = *(const short8v*)&Bs[cur][n * 32 + ((kg * 8) ^ ((n & 3) << 3))];
        }
#pragma unroll
        for (int i = 0; i < 4; i++)
#pragma unroll
            for (int j = 0; j < 4; j++)
                acc[i][j] = __builtin_amdgcn_mfma_f32_16x16x32_bf16(
                    a[i], b[j], acc[i][j], 0, 0, 0);

        if (t + 1 < NIT) {
            WRITE_A(nw, c1f0, c1f1);
            if (t + 3 < NIT)      vmwait<8>();
            else if (t + 2 < NIT) vmwait<4>();
            else                  vmwait<0>();
            lgkm0_barrier();
        }
        c1f0 = c2f0; c1f1 = c2f1;
        c2f0 = nf0;  c2f1 = nf1;
    }
#undef STAGE_B
#undef LOAD_A
#undef WRITE_A

    short* P = Part + (long)sk * NN * HH;
#pragma unroll
    for (int i = 0; i < 4; i++)
#pragma unroll
        for (int j = 0; j < 4; j++) {
            int col = wc * 64 + j * 16 + r16;
#pragma unroll
            for (int r = 0; r < 4; r++) {
                int row = m0 + wr * 64 + i * 16 + kg * 4 + r;
                P[(long)row * HH + col] = bf16bits(acc[i][j][r]);
            }
        }
}

// ---------------------------------------------------------------------------
// layer1 partial reduce (bf16 partials) -> bf16
// ---------------------------------------------------------------------------
__global__ __launch_bounds__(256) void reduceK(
    const short* __restrict__ P, short* __restrict__ out)
{
    const long n = (long)NN * HH;
    long i = ((long)blockIdx.x * 256 + threadIdx.x) * 8;
    if (i >= n) return;
    float acc[8] = {};
#pragma unroll
    for (int k = 0; k < SPLITK; k++) {
        short8v v = *(const short8v*)&P[(long)k * n + i];
#pragma unroll
        for (int j = 0; j < 8; j++) acc[j] += bits2f(v[j]);
    }
    short8v o;
#pragma unroll
    for (int j = 0; j < 8; j++) o[j] = bf16bits(acc[j]);
    *(short8v*)&out[i] = o;
}

// ---------------------------------------------------------------------------
// Small bf16 GEMM template, merged q/a sides + N-tiling for occupancy.
// BM=64, BN=NW*4, 256 threads, depth-3 (4-buffer) pipeline, counted vmcnt.
// A: bf16 [M][Kd] (optional gather). B: bf16 B^T [N][Kd] SW32 pre-swizzled.
// EPI: 1 = gram (bias+relu -> Xbf16 SW128 + per-batch XT SW128),
//      2 = plain f32 C (encoder).
// grid = (M/64) * NT * 2;  side = bid&1, nt = (bid>>1)&(NT-1), mt = bid>>(1+log2NT)
// ---------------------------------------------------------------------------
template<int NW, int NT, int GATHER, int EPI>
__global__ __launch_bounds__(256) void gemm_small(
    const short* __restrict__ Aq, const short* __restrict__ Aa,
    const short* __restrict__ Bt,
    float* __restrict__ Cfq, float* __restrict__ Cfa,
    short* __restrict__ Cbq, short* __restrict__ Cba,
    short* __restrict__ Ctq, short* __restrict__ Cta,
    const float* __restrict__ bias,
    const int* __restrict__ idxq, const int* __restrict__ idxa,
    int M, int N, int Kd)
{
    constexpr int BM = 64;
    constexpr int BN = NW * 4;
    constexpr int NB = NW / 16;
    constexpr int BCALLS = BN / BM;      // glds per B stage
    constexpr int OPS = 1 + BCALLS;      // vmem ops per stage (A reg-load + B)
    constexpr int AST = 40;

    __shared__ short As[4][BM * AST];
    __shared__ short Bs[4][BN * 32];

    const int tid = threadIdx.x;
    const int wave = tid >> 6, lane = tid & 63;
    const int wc = wave & 3;
    const int r16 = lane & 15, kg = lane >> 4;

    const int bid = blockIdx.x;
    const int side = bid & 1;
    const int nt = (bid >> 1) & (NT - 1);
    const int mt = bid >> (NT == 2 ? 2 : 1);
    const int m0 = mt * BM;
    const int n0 = nt * BN;
    const int niter = Kd / 32;

    const short* Ab = side ? Aa : Aq;
    const int* rowidx = side ? idxa : idxq;

    const int arow = tid >> 2;
    const int akc = (tid & 3) * 8;
    long arow_g;
    { int r = GATHER ? rowidx[m0 + arow] : (m0 + arow); arow_g = (long)r * Kd; }

    f32x4 acc[4][NB] = {};

#define STAGE_B(T, BUF)                                                        \
    {                                                                          \
        const int kt_ = (T) * 32;                                              \
        _Pragma("unroll")                                                      \
        for (int c = 0; c < BCALLS; c++) {                                     \
            int chunk = c * 256 + tid;                                         \
            int n_ = chunk >> 2, kc_ = (chunk & 3) * 8;                        \
            glds16(Bt + (long)(n0 + n_) * Kd + kt_ + kc_,                      \
                   &Bs[BUF][(c * 256 + wave * 64) * 8]);                       \
        }                                                                      \
    }
#define LOAD_A(T, AR)  { (AR) = *(const short8v*)(Ab + arow_g + (T) * 32 + akc); }
#define WRITE_A(BUF, AR) { *(short8v*)&As[BUF][arow * AST + akc] = (AR); }

    // prologue: tiles 0,1,2 (depth-3)
    short8v a0, a1, a2;
    LOAD_A(0, a0);  STAGE_B(0, 0);
    LOAD_A(1, a1);  STAGE_B(1, 1);
    LOAD_A(2, a2);  STAGE_B(2, 2);
    WRITE_A(0, a0);
    vmwait<2 * OPS>();
    lgkm0_barrier();

    for (int t = 0; t < niter; ++t) {
        const int cur = t & 3, nw = (t + 1) & 3, ns = (t + 3) & 3;
        short8v na;
        if (t + 3 < niter) {
            LOAD_A(t + 3, na);
            STAGE_B(t + 3, ns);
        }

        short8v a[4], b[NB];
#pragma unroll
        for (int i = 0; i < 4; i++)
            a[i] = *(const short8v*)&As[cur][(i * 16 + r16) * AST + kg * 8];
#pragma unroll
        for (int j = 0; j < NB; j++) {
            int n = wc * NW + j * 16 + r16;
            b[j] = *(const short8v*)&Bs[cur][n * 32 + ((kg * 8) ^ ((n & 3) << 3))];
        }
#pragma unroll
        for (int i = 0; i < 4; i++)
#pragma unroll
            for (int j = 0; j < NB; j++)
                acc[i][j] = __builtin_amdgcn_mfma_f32_16x16x32_bf16(
                    a[i], b[j], acc[i][j], 0, 0, 0);

        if (t + 1 < niter) {
            WRITE_A(nw, a1);
            if (t + 3 < niter)      vmwait<2 * OPS>();
            else if (t + 2 < niter) vmwait<OPS>();
            else                    vmwait<0>();
            lgkm0_barrier();
        }
        a1 = a2; a2 = na;
    }
#undef STAGE_B
#undef LOAD_A
#undef WRITE_A

    if (EPI == 2) {
        float* Cf = side ? Cfa : Cfq;
#pragma unroll
        for (int i = 0; i < 4; i++)
#pragma unroll
            for (int j = 0; j < NB; j++) {
                int col = n0 + wc * NW + j * 16 + r16;
#pragma unroll
                for (int r = 0; r < 4; r++) {
                    int row = m0 + i * 16 + kg * 4 + r;
                    Cf[(long)row * N + col] = acc[i][j][r];
                }
            }
    } else {   // EPI == 1: gram
        short* Cb = side ? Cba : Cbq;
        short* Ct = side ? Cta : Ctq;
#pragma unroll
        for (int i = 0; i < 4; i++)
#pragma unroll
            for (int j = 0; j < NB; j++) {
                int col = n0 + wc * NW + j * 16 + r16;
                float bv = bias[col];
                float vr[4];
#pragma unroll
                for (int r = 0; r < 4; r++)
                    vr[r] = fmaxf(acc[i][j][r] + bv, 0.f);
                int rbase = m0 + i * 16 + kg * 4;
                int bb = rbase >> 7;
                int lbase = rbase & 127;
#pragma unroll
                for (int r = 0; r < 4; r++) {
                    int grow = rbase + r;
                    Cb[(long)grow * 256 + (col ^ ((grow & 7) << 3))] = bf16bits(vr[r]);
                }
                short4v t4;
#pragma unroll
                for (int r = 0; r < 4; r++) t4[r] = bf16bits(vr[r]);
                int lsw = lbase ^ ((col & 7) << 3);
                *(short4v*)&Ct[(long)bb * (256 * 128) + col * 128 + lsw] = t4;
            }
    }
}

// ---------------------------------------------------------------------------
// qkT: per batch b, s[q][k] = Qm[b,q,:] . Am[b,k,:]  (bf16 MFMA, f32 out)
// ---------------------------------------------------------------------------
__global__ __launch_bounds__(256) void qkT(
    const short* __restrict__ Qb16, const short* __restrict__ Ab16,
    float* __restrict__ s)
{
    __shared__ short Q[128 * 256];
    __shared__ short Am[128 * 256];
    const int b = blockIdx.x;
    const int tid = threadIdx.x, wave = tid >> 6, lane = tid & 63;
    const int r16 = lane & 15, kg = lane >> 4;
    const long boff = (long)b * 128 * 256;

#pragma unroll
    for (int c = 0; c < 16; c++) {
        glds16(Qb16 + boff + ((long)c * 256 + tid) * 8, &Q[(c * 256 + wave * 64) * 8]);
        glds16(Ab16 + boff + ((long)c * 256 + tid) * 8, &Am[(c * 256 + wave * 64) * 8]);
    }
    __syncthreads();

    f32x4 acc[2][8] = {};
    const int q0 = wave * 32;
#pragma unroll
    for (int ks = 0; ks < 8; ks++) {
        short8v a[2], bf[8];
#pragma unroll
        for (int i = 0; i < 2; i++) {
            int q = q0 + i * 16 + r16;
            a[i] = *(const short8v*)&Q[q * 256 + ((ks * 32 + kg * 8) ^ ((q & 7) << 3))];
        }
#pragma unroll
        for (int j = 0; j < 8; j++) {
            int n = j * 16 + r16;
            bf[j] = *(const short8v*)&Am[n * 256 + ((ks * 32 + kg * 8) ^ ((n & 7) << 3))];
        }
#pragma unroll
        for (int i = 0; i < 2; i++)
#pragma unroll
            for (int j = 0; j < 8; j++)
                acc[i][j] = __builtin_amdgcn_mfma_f32_16x16x32_bf16(
                    a[i], bf[j], acc[i][j], 0, 0, 0);
    }

    float* sp = s + (long)b * 16384;
#pragma unroll
    for (int i = 0; i < 2; i++)
#pragma unroll
        for (int j = 0; j < 8; j++)
#pragma unroll
            for (int r = 0; r < 4; r++) {
                int q = q0 + i * 16 + kg * 4 + r;
                int k = j * 16 + r16;
                sp[q * 128 + k] = acc[i][j][r];
            }
}

// ---------------------------------------------------------------------------
// attn_pv merged (runtime side): softmax of s rows (side 0) / cols (side 1)
// -> P, E = P @ XT^T, fused t-features written bf16. grid = 128 (b, side).
// ---------------------------------------------------------------------------
__global__ __launch_bounds__(256) void attn_pv(
    const float* __restrict__ s,
    const short* __restrict__ AT, const short* __restrict__ QT,
    const short* __restrict__ Qb16, const short* __restrict__ Ab16,
    short* __restrict__ t_q, short* __restrict__ t_a)
{
    __shared__ float sm[128 * 128];   // 64 KB; reused for XT after softmax
    __shared__ short P[128 * 128];    // 32 KB
    short* XL = (short*)sm;
    const int b = blockIdx.x >> 1;
    const int side = blockIdx.x & 1;
    const int tid = threadIdx.x, wave = tid >> 6, lane = tid & 63;
    const int r16 = lane & 15, kg = lane >> 4;

    const short* XT   = side ? QT : AT;
    const short* Xrow = side ? Ab16 : Qb16;
    short* tout       = side ? t_a : t_q;

#pragma unroll
    for (int c = 0; c < 16; c++)
        glds16(s + (long)b * 16384 + ((long)c * 256 + tid) * 4,
               &sm[(c * 256 + wave * 64) * 4]);
    __syncthreads();

    {   // 2 threads per row, __shfl_xor(1) combine
        const int r = tid >> 1;
        const int base = (tid & 1) * 64;
        float mx = -1e30f;
#pragma unroll 8
        for (int i = 0; i < 64; i++) {
            int k = base + ((i + r) & 63);
            float v = side ? sm[k * 128 + r] : sm[r * 128 + k];
            mx = fmaxf(mx, v);
        }
        mx = fmaxf(mx, __shfl_xor(mx, 1));
        float sum = 0.f;
#pragma unroll 8
        for (int i = 0; i < 64; i++) {
            int k = base + ((i + r) & 63);
            float v = side ? sm[k * 128 + r] : sm[r * 128 + k];
            sum += __expf(v - mx);
        }
        sum += __shfl_xor(sum, 1);
        float inv = 1.f / sum;
#pragma unroll 8
        for (int i = 0; i < 64; i++) {
            int k = base + ((i + r) & 63);
            float v = side ? sm[k * 128 + r] : sm[r * 128 + k];
            P[r * 128 + (k ^ ((r & 7) << 3))] = bf16bits(__expf(v - mx) * inv);
        }
    }
    __syncthreads();

    // stage XT (overwrites sm)
#pragma unroll
    for (int c = 0; c < 16; c++)
        glds16(XT + (long)b * 32768 + ((long)c * 256 + tid) * 8,
               &XL[(c * 256 + wave * 64) * 8]);
    __syncthreads();

    f32x4 acc[8][4] = {};
#pragma unroll
    for (int ks = 0; ks < 4; ks++) {
        short8v a[8], bf[4];
#pragma unroll
        for (int i = 0; i < 8; i++) {
            int row = i * 16 + r16;
            a[i] = *(const short8v*)&P[row * 128 + ((ks * 32 + kg * 8) ^ ((row & 7) << 3))];
        }
#pragma unroll
        for (int j = 0; j < 4; j++) {
            int h = wave * 64 + j * 16 + r16;
            bf[j] = *(const short8v*)&XL[h * 128 + ((ks * 32 + kg * 8) ^ ((h & 7) << 3))];
        }
#pragma unroll
        for (int i = 0; i < 8; i++)
#pragma unroll
            for (int j = 0; j < 4; j++)
                acc[i][j] = __builtin_amdgcn_mfma_f32_16x16x32_bf16(
                    a[i], bf[j], acc[i][j], 0, 0, 0);
    }

    short* tp = tout + (long)b * 128 * 512;
    const short* xr = Xrow + (long)b * 128 * 256;
#pragma unroll
    for (int i = 0; i < 8; i++)
#pragma unroll
        for (int j = 0; j < 4; j++) {
            int col = wave * 64 + j * 16 + r16;
#pragma unroll
            for (int r = 0; r < 4; r++) {
                int row = i * 16 + kg * 4 + r;
                float E = acc[i][j][r];
                float x = bits2f(xr[row * 256 + (col ^ ((row & 7) << 3))]);
                float d = x - E;
                tp[(long)row * 512 + col] = bf16bits(d * d);
                tp[(long)row * 512 + 256 + col] = bf16bits(x * E);
            }
        }
}

// ---------------------------------------------------------------------------
// pool + final fused: re in LDS, then log_softmax(re @ Wd^T + bd)
// ---------------------------------------------------------------------------
__global__ __launch_bounds__(256) void pool_final(
    const float* __restrict__ u_q, const float* __restrict__ u_a,
    const float* __restrict__ b1, const float* __restrict__ b2,
    const float* __restrict__ Wd, const float* __restrict__ bd,
    float* __restrict__ out)
{
    __shared__ float re[512];
    const int b = blockIdx.x;
    const int t = threadIdx.x;
#pragma unroll
    for (int side = 0; side < 2; side++) {
        const float* uu = side ? u_a : u_q;
        if (t < 128) {
            int k = t;
            float bias = b1[k];
            float mx = -1e30f;
            for (int l = 0; l < 128; l++) {
                float v = uu[((long)b * 128 + l) * 384 + k] + bias;
                mx = fmaxf(mx, v);
            }
            re[side * 256 + k] = fmaxf(mx, 0.f);
        } else {
            int k = t - 128;
            float bias = b2[k];
            float mx = -1e30f;
            for (int l = 0; l < 127; l++) {
                float v = uu[((long)b * 128 + l) * 384 + 128 + k]
                        + uu[((long)b * 128 + l + 1) * 384 + 256 + k] + bias;
                mx = fmaxf(mx, v);
            }
            re[side * 256 + 128 + k] = fmaxf(mx, 0.f);
        }
    }
    __syncthreads();
    if (t < 64) {
        float p0 = 0.f, p1 = 0.f;
        for (int d = t; d < 512; d += 64) {
            float r = re[d];
            p0 = fmaf(r, Wd[d], p0);
            p1 = fmaf(r, Wd[512 + d], p1);
        }
#pragma unroll
        for (int off = 32; off; off >>= 1) {
            p0 += __shfl_xor(p0, off);
            p1 += __shfl_xor(p1, off);
        }
        if (t == 0) {
            float l0 = p0 + bd[0], l1 = p1 + bd[1];
            float m = fmaxf(l0, l1);
            float lse = m + logf(expf(l0 - m) + expf(l1 - m));
            out[b * 2 + 0] = l0 - lse;
            out[b * 2 + 1] = l1 - lse;
        }
    }
}

// ---------------------------------------------------------------------------
extern "C" void kernel_launch(void* const* d_in, const int* in_sizes, int n_in,
                              void* d_out, int out_size, void* d_ws, size_t ws_size,
                              hipStream_t stream)
{
    const float* A    = (const float*)d_in[0];
    const float* emb  = (const float*)d_in[1];
    const float* Wc   = (const float*)d_in[2];
    const float* bc   = (const float*)d_in[3];
    const float* W1   = (const float*)d_in[4];
    const float* b1   = (const float*)d_in[5];
    const float* W2   = (const float*)d_in[6];
    const float* b2   = (const float*)d_in[7];
    const float* Wd   = (const float*)d_in[8];
    const float* bd   = (const float*)d_in[9];
    const int* q_idx  = (const int*)d_in[10];
    const int* a_idx  = (const int*)d_in[11];
    float* out = (float*)d_out;
    float* ws  = (float*)d_ws;

    // workspace layout (float units)
    const long SZ_L1 = (long)NN * HH;                 // 2,097,152
    float* p      = ws;
    short* Part   = (short*)p;          p += (long)SPLITK * SZ_L1 / 2;  // bf16
    short* l1b    = (short*)p;          p += SZ_L1 / 2 + 1024;   // bf16 [8192][256]
    short* Wcb    = (short*)p;          p += 32768 + 1024;       // bf16 [256][256] SW32
    short* WcatT  = (short*)p;          p += 98304 + 1024;       // bf16 [384][512] SW32
    short* embT   = (short*)p;          p += SZ_L1 / 2 + 1024;   // bf16 [256][8192] SW32
    short* Qb16   = (short*)p;          p += SZ_L1 / 2 + 1024;   // bf16 [8192][256] SW128
    short* Ab16   = (short*)p;          p += SZ_L1 / 2 + 1024;
    short* QT     = (short*)p;          p += SZ_L1 / 2 + 1024;   // bf16 [64][256][128] SW128
    short* AT     = (short*)p;          p += SZ_L1 / 2 + 1024;
    float* s      = p;                  p += (long)BB * LL * LL; // f32 [64][128][128]
    short* t_q    = (short*)p;          p += SZ_L1 + 1024;       // bf16 [8192][512]
    short* t_a    = (short*)p;          p += SZ_L1 + 1024;
    float* u_q    = p;                  p += (long)BB * LL * 384;
    float* u_a    = p;                  p += (long)BB * LL * 384;

    // 1. weight packing + emb transpose
    prep<<<1280, 256, 0, stream>>>(emb, embT, Wc, Wcb, W1, W2, WcatT);

    // 2. layer1: R7-proven pipeline, splitK=8, 512 blocks
    l1_gemm<<<512, 512, 0, stream>>>(A, embT, Part);
    reduceK<<<(int)(SZ_L1 / 8 / 256), 256, 0, stream>>>(Part, l1b);

    // 3. gram merged q+a: BN=128 x 2 n-tiles x 2 sides = 512 blocks
    gemm_small<32, 2, 1, 1><<<512, 256, 0, stream>>>(
        l1b, l1b, Wcb, nullptr, nullptr, Qb16, Ab16, QT, AT, bc,
        q_idx, a_idx, BB * LL, HH, HH);

    // 4. attention
    qkT<<<BB, 256, 0, stream>>>(Qb16, Ab16, s);
    attn_pv<<<2 * BB, 256, 0, stream>>>(s, AT, QT, Qb16, Ab16, t_q, t_a);

    // 5. encoder merged q+a: BN=192 x 2 n-tiles x 2 sides = 512 blocks
    gemm_small<48, 2, 0, 2><<<512, 256, 0, stream>>>(
        t_q, t_a, WcatT, u_q, u_a, nullptr, nullptr, nullptr, nullptr, nullptr,
        nullptr, nullptr, BB * LL, 384, 512);

    // 6. pool + final
    pool_final<<<BB, 256, 0, stream>>>(u_q, u_a, b1, b2, Wd, bd, out);
}

// Round 10
// 200.228 us; speedup vs baseline: 1.6743x; 1.1354x over previous
//
#include <hip/hip_runtime.h>
#include <hip/hip_bf16.h>
#include <math.h>

// Problem constants
#define NN 8192
#define HH 256
#define BB 64
#define LL 128
#define SPLITK 4

typedef __attribute__((ext_vector_type(8))) short short8v;   // 8 bf16
typedef __attribute__((ext_vector_type(4))) short short4v;   // 4 bf16
typedef __attribute__((ext_vector_type(4))) float f32x4;     // MFMA acc

static __device__ inline short bf16bits(float f) {
    __hip_bfloat16 h = __float2bfloat16(f);
    return __builtin_bit_cast(short, h);
}
static __device__ inline float bits2f(short s) {
    __hip_bfloat16 h = __builtin_bit_cast(__hip_bfloat16, s);
    return __bfloat162float(h);
}
static __device__ inline short8v cvt8(float4 f0, float4 f1) {
    short8v r;
    r[0] = bf16bits(f0.x); r[1] = bf16bits(f0.y);
    r[2] = bf16bits(f0.z); r[3] = bf16bits(f0.w);
    r[4] = bf16bits(f1.x); r[5] = bf16bits(f1.y);
    r[6] = bf16bits(f1.z); r[7] = bf16bits(f1.w);
    return r;
}
// async global -> LDS, 16 B/lane, linear dest (wave-uniform base + lane*16)
static __device__ inline void glds16(const void* src, void* lds) {
    __builtin_amdgcn_global_load_lds(
        (const __attribute__((address_space(1))) void*)src,
        (__attribute__((address_space(3))) void*)lds, 16, 0, 0);
}
template<int N> static __device__ inline void vmwait() {
    if constexpr (N == 0)  asm volatile("s_waitcnt vmcnt(0)"  ::: "memory");
    else if constexpr (N == 1)  asm volatile("s_waitcnt vmcnt(1)"  ::: "memory");
    else if constexpr (N == 2)  asm volatile("s_waitcnt vmcnt(2)"  ::: "memory");
    else if constexpr (N == 3)  asm volatile("s_waitcnt vmcnt(3)"  ::: "memory");
    else if constexpr (N == 4)  asm volatile("s_waitcnt vmcnt(4)"  ::: "memory");
    else if constexpr (N == 5)  asm volatile("s_waitcnt vmcnt(5)"  ::: "memory");
    else if constexpr (N == 6)  asm volatile("s_waitcnt vmcnt(6)"  ::: "memory");
    else if constexpr (N == 7)  asm volatile("s_waitcnt vmcnt(7)"  ::: "memory");
    else if constexpr (N == 8)  asm volatile("s_waitcnt vmcnt(8)"  ::: "memory");
    else                        asm volatile("s_waitcnt vmcnt(12)" ::: "memory");
}
static __device__ inline void lgkm0_barrier() {
    asm volatile("s_waitcnt lgkmcnt(0)" ::: "memory");
    __builtin_amdgcn_s_barrier();
    __builtin_amdgcn_sched_barrier(0);
}

// Swizzle conventions:
//  SW32  (rows consumed in [*][32]-short LDS tiles): chunk k ^= (row&3)<<3
//  SW128 (rows of >=128 shorts): k ^= (row&7)<<3

// ---------------------------------------------------------------------------
// prep: emb [8192][256] f32 -> embT [256][8192] bf16 SW32 (blocks 0..511)
//       weight packing to bf16 B^T SW32 (blocks 512..1279)
// ---------------------------------------------------------------------------
__global__ __launch_bounds__(256) void prep(
    const float* __restrict__ emb, short* __restrict__ embT,
    const float* __restrict__ Wc, short* __restrict__ Wcb,
    const float* __restrict__ W1, const float* __restrict__ W2,
    short* __restrict__ WcatT)
{
    __shared__ short tile[64][65];
    const int bid = blockIdx.x;
    const int t = threadIdx.x;
    if (bid < 512) {
        const int k0 = (bid & 127) * 64, h0 = (bid >> 7) * 64;
#pragma unroll
        for (int i = 0; i < 16; i++) {
            int idx = t + i * 256;
            int k = idx >> 6, h = idx & 63;
            tile[h][k] = bf16bits(emb[(long)(k0 + k) * 256 + h0 + h]);
        }
        __syncthreads();
#pragma unroll
        for (int i = 0; i < 16; i++) {
            int idx = t + i * 256;
            int h = idx >> 6, k = idx & 63;
            int n = h0 + h;
            int kk = (k0 + k) ^ ((n & 3) << 3);   // SW32
            embT[(long)n * NN + kk] = tile[h][k];
        }
    } else {
        int i = (bid - 512) * 256 + t;
        if (i < 256 * 256) {
            int n = i >> 8, c = i & 255;
            Wcb[n * 256 + (c ^ ((n & 3) << 3))] = bf16bits(Wc[i]);
        }
        if (i < 384 * 512) {
            int n = i >> 9, d = i & 511;
            float v;
            if (n < 128)      v = W1[n * 512 + d];
            else if (n < 256) v = W2[(n - 128) * 1024 + d];
            else              v = W2[(n - 256) * 1024 + 512 + d];
            WcatT[n * 512 + (d ^ ((n & 3) << 3))] = bf16bits(v);
        }
    }
}

// ---------------------------------------------------------------------------
// layer1 = A(f32) @ embT^T -> bf16 partials. BM=128, BN=256, splitK=4.
// 4-buffer depth-3 pipeline, A f32 reg-stage + cvt into padded LDS,
// B glds SW32, counted vmcnt, raw barriers. 8 waves (2m x 4n). grid=256.
// ---------------------------------------------------------------------------
__global__ __launch_bounds__(512, 2) void l1_gemm(
    const float* __restrict__ Af, const short* __restrict__ Bt,
    short* __restrict__ Part)
{
    constexpr int AST = 40;              // padded A row stride (shorts)

    __shared__ short As[4][128 * AST];
    __shared__ short Bs[4][256 * 32];

    const int tid = threadIdx.x;
    const int wave = tid >> 6, lane = tid & 63;
    const int wr = wave >> 2, wc = wave & 3;
    const int r16 = lane & 15, kg = lane >> 4;

    const int sk = blockIdx.x & 3, mt = blockIdx.x >> 2;   // XCD keeps one sk slice
    const int m0 = mt * 128;
    const int kbeg = sk * 2048;
    constexpr int NIT = 64;              // 2048 / 32

    const int arow = tid >> 2;
    const int akc = (tid & 3) * 8;
    const long arow_g = (long)(m0 + arow) * NN;

    f32x4 acc[4][4] = {};

#define STAGE_B(T, BUF)                                                        \
    {                                                                          \
        const int kt_ = kbeg + (T) * 32;                                       \
        _Pragma("unroll")                                                      \
        for (int c = 0; c < 2; c++) {                                          \
            int chunk = c * 512 + tid;                                         \
            int n_ = chunk >> 2, kc_ = (chunk & 3) * 8;                        \
            glds16(Bt + (long)n_ * NN + kt_ + kc_,                             \
                   &Bs[BUF][(c * 512 + wave * 64) * 8]);                       \
        }                                                                      \
    }
#define LOAD_A(T, F0, F1)                                                      \
    {                                                                          \
        const float* ap_ = Af + arow_g + kbeg + (T) * 32 + akc;                \
        (F0) = *(const float4*)ap_; (F1) = *(const float4*)(ap_ + 4);          \
    }
#define WRITE_A(BUF, F0, F1) { *(short8v*)&As[BUF][arow * AST + akc] = cvt8((F0), (F1)); }

    // prologue: tiles 0,1,2 (depth-3)
    float4 p0f0, p0f1, c1f0, c1f1, c2f0, c2f1;
    LOAD_A(0, p0f0, p0f1);  STAGE_B(0, 0);
    LOAD_A(1, c1f0, c1f1);  STAGE_B(1, 1);
    LOAD_A(2, c2f0, c2f1);  STAGE_B(2, 2);
    WRITE_A(0, p0f0, p0f1);
    vmwait<8>();            // drain tile-0 glds; tiles 1,2 stay in flight
    lgkm0_barrier();

    for (int t = 0; t < NIT; ++t) {
        const int cur = t & 3, nw = (t + 1) & 3, ns = (t + 3) & 3;
        float4 nf0, nf1;
        if (t + 3 < NIT) {
            LOAD_A(t + 3, nf0, nf1);
            STAGE_B(t + 3, ns);
        }

        short8v a[4], b[4];
#pragma unroll
        for (int i = 0; i < 4; i++)
            a[i] = *(const short8v*)&As[cur][(wr * 64 + i * 16 + r16) * AST + kg * 8];
#pragma unroll
        for (int j = 0; j < 4; j++) {
            int n = wc * 64 + j * 16 + r16;
            b[j] = *(const short8v*)&Bs[cur][n * 32 + ((kg * 8) ^ ((n & 3) << 3))];
        }
#pragma unroll
        for (int i = 0; i < 4; i++)
#pragma unroll
            for (int j = 0; j < 4; j++)
                acc[i][j] = __builtin_amdgcn_mfma_f32_16x16x32_bf16(
                    a[i], b[j], acc[i][j], 0, 0, 0);

        if (t + 1 < NIT) {
            WRITE_A(nw, c1f0, c1f1);
            if (t + 3 < NIT)      vmwait<8>();
            else if (t + 2 < NIT) vmwait<4>();
            else                  vmwait<0>();
            lgkm0_barrier();
        }
        c1f0 = c2f0; c1f1 = c2f1;
        c2f0 = nf0;  c2f1 = nf1;
    }
#undef STAGE_B
#undef LOAD_A
#undef WRITE_A

    short* P = Part + (long)sk * NN * HH;
#pragma unroll
    for (int i = 0; i < 4; i++)
#pragma unroll
        for (int j = 0; j < 4; j++) {
            int col = wc * 64 + j * 16 + r16;
#pragma unroll
            for (int r = 0; r < 4; r++) {
                int row = m0 + wr * 64 + i * 16 + kg * 4 + r;
                P[(long)row * HH + col] = bf16bits(acc[i][j][r]);
            }
        }
}

// ---------------------------------------------------------------------------
// layer1 partial reduce (bf16 partials) -> bf16
// ---------------------------------------------------------------------------
__global__ __launch_bounds__(256) void reduceK(
    const short* __restrict__ P, short* __restrict__ out)
{
    const long n = (long)NN * HH;
    long i = ((long)blockIdx.x * 256 + threadIdx.x) * 8;
    if (i >= n) return;
    float acc[8] = {};
#pragma unroll
    for (int k = 0; k < SPLITK; k++) {
        short8v v = *(const short8v*)&P[(long)k * n + i];
#pragma unroll
        for (int j = 0; j < 8; j++) acc[j] += bits2f(v[j]);
    }
    short8v o;
#pragma unroll
    for (int j = 0; j < 8; j++) o[j] = bf16bits(acc[j]);
    *(short8v*)&out[i] = o;
}

// ---------------------------------------------------------------------------
// Small bf16 GEMM template, merged q/a sides + N-tiling for occupancy.
// BM=64, BN=NW*4, 256 threads, depth-3 (4-buffer) pipeline, counted vmcnt.
// A: bf16 [M][Kd] (optional gather). B: bf16 B^T [N][Kd] SW32 pre-swizzled.
// EPI: 1 = gram (bias+relu -> Xbf16 SW128 + per-batch XT SW128),
//      2 = plain f32 C (encoder).
// grid = (M/64) * NT * 2;  side = bid&1, nt = (bid>>1)&(NT-1), mt = bid>>(1+log2NT)
// ---------------------------------------------------------------------------
template<int NW, int NT, int GATHER, int EPI>
__global__ __launch_bounds__(256) void gemm_small(
    const short* __restrict__ Aq, const short* __restrict__ Aa,
    const short* __restrict__ Bt,
    float* __restrict__ Cfq, float* __restrict__ Cfa,
    short* __restrict__ Cbq, short* __restrict__ Cba,
    short* __restrict__ Ctq, short* __restrict__ Cta,
    const float* __restrict__ bias,
    const int* __restrict__ idxq, const int* __restrict__ idxa,
    int M, int N, int Kd)
{
    constexpr int BM = 64;
    constexpr int BN = NW * 4;
    constexpr int NB = NW / 16;
    constexpr int BCALLS = BN / BM;      // glds per B stage
    constexpr int OPS = 1 + BCALLS;      // vmem ops per stage (A reg-load + B)
    constexpr int AST = 40;

    __shared__ short As[4][BM * AST];
    __shared__ short Bs[4][BN * 32];

    const int tid = threadIdx.x;
    const int wave = tid >> 6, lane = tid & 63;
    const int wc = wave & 3;
    const int r16 = lane & 15, kg = lane >> 4;

    const int bid = blockIdx.x;
    const int side = bid & 1;
    const int nt = (bid >> 1) & (NT - 1);
    const int mt = bid >> (NT == 2 ? 2 : 1);
    const int m0 = mt * BM;
    const int n0 = nt * BN;
    const int niter = Kd / 32;

    const short* Ab = side ? Aa : Aq;
    const int* rowidx = side ? idxa : idxq;

    const int arow = tid >> 2;
    const int akc = (tid & 3) * 8;
    long arow_g;
    { int r = GATHER ? rowidx[m0 + arow] : (m0 + arow); arow_g = (long)r * Kd; }

    f32x4 acc[4][NB] = {};

#define STAGE_B(T, BUF)                                                        \
    {                                                                          \
        const int kt_ = (T) * 32;                                              \
        _Pragma("unroll")                                                      \
        for (int c = 0; c < BCALLS; c++) {                                     \
            int chunk = c * 256 + tid;                                         \
            int n_ = chunk >> 2, kc_ = (chunk & 3) * 8;                        \
            glds16(Bt + (long)(n0 + n_) * Kd + kt_ + kc_,                      \
                   &Bs[BUF][(c * 256 + wave * 64) * 8]);                       \
        }                                                                      \
    }
#define LOAD_A(T, AR)  { (AR) = *(const short8v*)(Ab + arow_g + (T) * 32 + akc); }
#define WRITE_A(BUF, AR) { *(short8v*)&As[BUF][arow * AST + akc] = (AR); }

    // prologue: tiles 0,1,2 (depth-3)
    short8v a0, a1, a2;
    LOAD_A(0, a0);  STAGE_B(0, 0);
    LOAD_A(1, a1);  STAGE_B(1, 1);
    LOAD_A(2, a2);  STAGE_B(2, 2);
    WRITE_A(0, a0);
    vmwait<2 * OPS>();
    lgkm0_barrier();

    for (int t = 0; t < niter; ++t) {
        const int cur = t & 3, nw = (t + 1) & 3, ns = (t + 3) & 3;
        short8v na;
        if (t + 3 < niter) {
            LOAD_A(t + 3, na);
            STAGE_B(t + 3, ns);
        }

        short8v a[4], b[NB];
#pragma unroll
        for (int i = 0; i < 4; i++)
            a[i] = *(const short8v*)&As[cur][(i * 16 + r16) * AST + kg * 8];
#pragma unroll
        for (int j = 0; j < NB; j++) {
            int n = wc * NW + j * 16 + r16;
            b[j] = *(const short8v*)&Bs[cur][n * 32 + ((kg * 8) ^ ((n & 3) << 3))];
        }
#pragma unroll
        for (int i = 0; i < 4; i++)
#pragma unroll
            for (int j = 0; j < NB; j++)
                acc[i][j] = __builtin_amdgcn_mfma_f32_16x16x32_bf16(
                    a[i], b[j], acc[i][j], 0, 0, 0);

        if (t + 1 < niter) {
            WRITE_A(nw, a1);
            if (t + 3 < niter)      vmwait<2 * OPS>();
            else if (t + 2 < niter) vmwait<OPS>();
            else                    vmwait<0>();
            lgkm0_barrier();
        }
        a1 = a2; a2 = na;
    }
#undef STAGE_B
#undef LOAD_A
#undef WRITE_A

    if (EPI == 2) {
        float* Cf = side ? Cfa : Cfq;
#pragma unroll
        for (int i = 0; i < 4; i++)
#pragma unroll
            for (int j = 0; j < NB; j++) {
                int col = n0 + wc * NW + j * 16 + r16;
#pragma unroll
                for (int r = 0; r < 4; r++) {
                    int row = m0 + i * 16 + kg * 4 + r;
                    Cf[(long)row * N + col] = acc[i][j][r];
                }
            }
    } else {   // EPI == 1: gram
        short* Cb = side ? Cba : Cbq;
        short* Ct = side ? Cta : Ctq;
#pragma unroll
        for (int i = 0; i < 4; i++)
#pragma unroll
            for (int j = 0; j < NB; j++) {
                int col = n0 + wc * NW + j * 16 + r16;
                float bv = bias[col];
                float vr[4];
#pragma unroll
                for (int r = 0; r < 4; r++)
                    vr[r] = fmaxf(acc[i][j][r] + bv, 0.f);
                int rbase = m0 + i * 16 + kg * 4;
                int bb = rbase >> 7;
                int lbase = rbase & 127;
#pragma unroll
                for (int r = 0; r < 4; r++) {
                    int grow = rbase + r;
                    Cb[(long)grow * 256 + (col ^ ((grow & 7) << 3))] = bf16bits(vr[r]);
                }
                short4v t4;
#pragma unroll
                for (int r = 0; r < 4; r++) t4[r] = bf16bits(vr[r]);
                int lsw = lbase ^ ((col & 7) << 3);
                *(short4v*)&Ct[(long)bb * (256 * 128) + col * 128 + lsw] = t4;
            }
    }
}

// ---------------------------------------------------------------------------
// qkT: per (batch, q-half): s[q][k] = Qm[b,q,:] . Am[b,k,:]  (bf16 MFMA)
// grid = 2*BB. Q-half 64 rows (32 KB) + Am full (64 KB) in LDS.
// ---------------------------------------------------------------------------
__global__ __launch_bounds__(256) void qkT(
    const short* __restrict__ Qb16, const short* __restrict__ Ab16,
    float* __restrict__ s)
{
    __shared__ short Q[64 * 256];     // 32 KB
    __shared__ short Am[128 * 256];   // 64 KB
    const int b = blockIdx.x >> 1;
    const int qh = blockIdx.x & 1;
    const int tid = threadIdx.x, wave = tid >> 6, lane = tid & 63;
    const int r16 = lane & 15, kg = lane >> 4;
    const long boff = (long)b * 128 * 256;
    const long qoff = boff + (long)qh * 64 * 256;

#pragma unroll
    for (int c = 0; c < 8; c++)
        glds16(Qb16 + qoff + ((long)c * 256 + tid) * 8, &Q[(c * 256 + wave * 64) * 8]);
#pragma unroll
    for (int c = 0; c < 16; c++)
        glds16(Ab16 + boff + ((long)c * 256 + tid) * 8, &Am[(c * 256 + wave * 64) * 8]);
    __syncthreads();

    f32x4 acc[8] = {};
    const int q0 = wave * 16;
#pragma unroll
    for (int ks = 0; ks < 8; ks++) {
        short8v a;
        {
            int q = q0 + r16;
            a = *(const short8v*)&Q[q * 256 + ((ks * 32 + kg * 8) ^ ((q & 7) << 3))];
        }
#pragma unroll
        for (int j = 0; j < 8; j++) {
            int n = j * 16 + r16;
            short8v bf = *(const short8v*)&Am[n * 256 + ((ks * 32 + kg * 8) ^ ((n & 7) << 3))];
            acc[j] = __builtin_amdgcn_mfma_f32_16x16x32_bf16(a, bf, acc[j], 0, 0, 0);
        }
    }

    float* sp = s + (long)b * 16384 + (long)qh * 64 * 128;
#pragma unroll
    for (int j = 0; j < 8; j++)
#pragma unroll
        for (int r = 0; r < 4; r++) {
            int q = q0 + kg * 4 + r;
            int k = j * 16 + r16;
            sp[q * 128 + k] = acc[j][r];
        }
}

// ---------------------------------------------------------------------------
// attn_pv merged (runtime side): softmax of s rows (side 0) / cols (side 1)
// -> P, E = P @ XT^T, fused t-features written bf16. grid = 128 (b, side).
// ---------------------------------------------------------------------------
__global__ __launch_bounds__(256) void attn_pv(
    const float* __restrict__ s,
    const short* __restrict__ AT, const short* __restrict__ QT,
    const short* __restrict__ Qb16, const short* __restrict__ Ab16,
    short* __restrict__ t_q, short* __restrict__ t_a)
{
    __shared__ float sm[128 * 128];   // 64 KB; reused for XT after softmax
    __shared__ short P[128 * 128];    // 32 KB
    short* XL = (short*)sm;
    const int b = blockIdx.x >> 1;
    const int side = blockIdx.x & 1;
    const int tid = threadIdx.x, wave = tid >> 6, lane = tid & 63;
    const int r16 = lane & 15, kg = lane >> 4;

    const short* XT   = side ? QT : AT;
    const short* Xrow = side ? Ab16 : Qb16;
    short* tout       = side ? t_a : t_q;

#pragma unroll
    for (int c = 0; c < 16; c++)
        glds16(s + (long)b * 16384 + ((long)c * 256 + tid) * 4,
               &sm[(c * 256 + wave * 64) * 4]);
    __syncthreads();

    {   // 2 threads per row, __shfl_xor(1) combine
        const int r = tid >> 1;
        const int base = (tid & 1) * 64;
        float mx = -1e30f;
#pragma unroll 8
        for (int i = 0; i < 64; i++) {
            int k = base + ((i + r) & 63);
            float v = side ? sm[k * 128 + r] : sm[r * 128 + k];
            mx = fmaxf(mx, v);
        }
        mx = fmaxf(mx, __shfl_xor(mx, 1));
        float sum = 0.f;
#pragma unroll 8
        for (int i = 0; i < 64; i++) {
            int k = base + ((i + r) & 63);
            float v = side ? sm[k * 128 + r] : sm[r * 128 + k];
            sum += __expf(v - mx);
        }
        sum += __shfl_xor(sum, 1);
        float inv = 1.f / sum;
#pragma unroll 8
        for (int i = 0; i < 64; i++) {
            int k = base + ((i + r) & 63);
            float v = side ? sm[k * 128 + r] : sm[r * 128 + k];
            P[r * 128 + (k ^ ((r & 7) << 3))] = bf16bits(__expf(v - mx) * inv);
        }
    }
    __syncthreads();

    // stage XT (overwrites sm)
#pragma unroll
    for (int c = 0; c < 16; c++)
        glds16(XT + (long)b * 32768 + ((long)c * 256 + tid) * 8,
               &XL[(c * 256 + wave * 64) * 8]);
    __syncthreads();

    f32x4 acc[8][4] = {};
#pragma unroll
    for (int ks = 0; ks < 4; ks++) {
        short8v a[8], bf[4];
#pragma unroll
        for (int i = 0; i < 8; i++) {
            int row = i * 16 + r16;
            a[i] = *(const short8v*)&P[row * 128 + ((ks * 32 + kg * 8) ^ ((row & 7) << 3))];
        }
#pragma unroll
        for (int j = 0; j < 4; j++) {
            int h = wave * 64 + j * 16 + r16;
            bf[j] = *(const short8v*)&XL[h * 128 + ((ks * 32 + kg * 8) ^ ((h & 7) << 3))];
        }
#pragma unroll
        for (int i = 0; i < 8; i++)
#pragma unroll
            for (int j = 0; j < 4; j++)
                acc[i][j] = __builtin_amdgcn_mfma_f32_16x16x32_bf16(
                    a[i], bf[j], acc[i][j], 0, 0, 0);
    }

    short* tp = tout + (long)b * 128 * 512;
    const short* xr = Xrow + (long)b * 128 * 256;
#pragma unroll
    for (int i = 0; i < 8; i++)
#pragma unroll
        for (int j = 0; j < 4; j++) {
            int col = wave * 64 + j * 16 + r16;
#pragma unroll
            for (int r = 0; r < 4; r++) {
                int row = i * 16 + kg * 4 + r;
                float E = acc[i][j][r];
                float x = bits2f(xr[row * 256 + (col ^ ((row & 7) << 3))]);
                float d = x - E;
                tp[(long)row * 512 + col] = bf16bits(d * d);
                tp[(long)row * 512 + 256 + col] = bf16bits(x * E);
            }
        }
}

// ---------------------------------------------------------------------------
// pool + final fused: 512 threads, one (side,k) pair per thread.
// ---------------------------------------------------------------------------
__global__ __launch_bounds__(512) void pool_final(
    const float* __restrict__ u_q, const float* __restrict__ u_a,
    const float* __restrict__ b1, const float* __restrict__ b2,
    const float* __restrict__ Wd, const float* __restrict__ bd,
    float* __restrict__ out)
{
    __shared__ float re[512];
    const int b = blockIdx.x;
    const int t = threadIdx.x;
    const int side = t >> 8;
    const int kk = t & 255;
    const float* uu = side ? u_a : u_q;
    if (kk < 128) {
        int k = kk;
        float bias = b1[k];
        float mx = -1e30f;
        for (int l = 0; l < 128; l++) {
            float v = uu[((long)b * 128 + l) * 384 + k] + bias;
            mx = fmaxf(mx, v);
        }
        re[side * 256 + k] = fmaxf(mx, 0.f);
    } else {
        int k = kk - 128;
        float bias = b2[k];
        float mx = -1e30f;
        for (int l = 0; l < 127; l++) {
            float v = uu[((long)b * 128 + l) * 384 + 128 + k]
                    + uu[((long)b * 128 + l + 1) * 384 + 256 + k] + bias;
            mx = fmaxf(mx, v);
        }
        re[side * 256 + 128 + k] = fmaxf(mx, 0.f);
    }
    __syncthreads();
    if (t < 64) {
        float p0 = 0.f, p1 = 0.f;
        for (int d = t; d < 512; d += 64) {
            float r = re[d];
            p0 = fmaf(r, Wd[d], p0);
            p1 = fmaf(r, Wd[512 + d], p1);
        }
#pragma unroll
        for (int off = 32; off; off >>= 1) {
            p0 += __shfl_xor(p0, off);
            p1 += __shfl_xor(p1, off);
        }
        if (t == 0) {
            float l0 = p0 + bd[0], l1 = p1 + bd[1];
            float m = fmaxf(l0, l1);
            float lse = m + logf(expf(l0 - m) + expf(l1 - m));
            out[b * 2 + 0] = l0 - lse;
            out[b * 2 + 1] = l1 - lse;
        }
    }
}

// ---------------------------------------------------------------------------
extern "C" void kernel_launch(void* const* d_in, const int* in_sizes, int n_in,
                              void* d_out, int out_size, void* d_ws, size_t ws_size,
                              hipStream_t stream)
{
    const float* A    = (const float*)d_in[0];
    const float* emb  = (const float*)d_in[1];
    const float* Wc   = (const float*)d_in[2];
    const float* bc   = (const float*)d_in[3];
    const float* W1   = (const float*)d_in[4];
    const float* b1   = (const float*)d_in[5];
    const float* W2   = (const float*)d_in[6];
    const float* b2   = (const float*)d_in[7];
    const float* Wd   = (const float*)d_in[8];
    const float* bd   = (const float*)d_in[9];
    const int* q_idx  = (const int*)d_in[10];
    const int* a_idx  = (const int*)d_in[11];
    float* out = (float*)d_out;
    float* ws  = (float*)d_ws;

    // workspace layout (float units)
    const long SZ_L1 = (long)NN * HH;                 // 2,097,152
    float* p      = ws;
    short* Part   = (short*)p;          p += (long)SPLITK * SZ_L1 / 2;  // bf16
    short* l1b    = (short*)p;          p += SZ_L1 / 2 + 1024;   // bf16 [8192][256]
    short* Wcb    = (short*)p;          p += 32768 + 1024;       // bf16 [256][256] SW32
    short* WcatT  = (short*)p;          p += 98304 + 1024;       // bf16 [384][512] SW32
    short* embT   = (short*)p;          p += SZ_L1 / 2 + 1024;   // bf16 [256][8192] SW32
    short* Qb16   = (short*)p;          p += SZ_L1 / 2 + 1024;   // bf16 [8192][256] SW128
    short* Ab16   = (short*)p;          p += SZ_L1 / 2 + 1024;
    short* QT     = (short*)p;          p += SZ_L1 / 2 + 1024;   // bf16 [64][256][128] SW128
    short* AT     = (short*)p;          p += SZ_L1 / 2 + 1024;
    float* s      = p;                  p += (long)BB * LL * LL; // f32 [64][128][128]
    short* t_q    = (short*)p;          p += SZ_L1 + 1024;       // bf16 [8192][512]
    short* t_a    = (short*)p;          p += SZ_L1 + 1024;
    float* u_q    = p;                  p += (long)BB * LL * 384;
    float* u_a    = p;                  p += (long)BB * LL * 384;

    // 1. weight packing + emb transpose
    prep<<<1280, 256, 0, stream>>>(emb, embT, Wc, Wcb, W1, W2, WcatT);

    // 2. layer1: splitK=4, 256 blocks (1/CU)
    l1_gemm<<<256, 512, 0, stream>>>(A, embT, Part);
    reduceK<<<(int)(SZ_L1 / 8 / 256), 256, 0, stream>>>(Part, l1b);

    // 3. gram merged q+a: BN=128 x 2 n-tiles x 2 sides = 512 blocks
    gemm_small<32, 2, 1, 1><<<512, 256, 0, stream>>>(
        l1b, l1b, Wcb, nullptr, nullptr, Qb16, Ab16, QT, AT, bc,
        q_idx, a_idx, BB * LL, HH, HH);

    // 4. attention: qkT split by q-half (128 blocks), attn_pv merged (128)
    qkT<<<2 * BB, 256, 0, stream>>>(Qb16, Ab16, s);
    attn_pv<<<2 * BB, 256, 0, stream>>>(s, AT, QT, Qb16, Ab16, t_q, t_a);

    // 5. encoder merged q+a: BN=192 x 2 n-tiles x 2 sides = 512 blocks
    gemm_small<48, 2, 0, 2><<<512, 256, 0, stream>>>(
        t_q, t_a, WcatT, u_q, u_a, nullptr, nullptr, nullptr, nullptr, nullptr,
        nullptr, nullptr, BB * LL, 384, 512);

    // 6. pool + final
    pool_final<<<BB, 512, 0, stream>>>(u_q, u_a, b1, b2, Wd, bd, out);
}

// Round 12
// 175.588 us; speedup vs baseline: 1.9092x; 1.1403x over previous
//
#include <hip/hip_runtime.h>
#include <hip/hip_bf16.h>
#include <math.h>

// Problem constants
#define NN 8192
#define HH 256
#define BB 64
#define LL 128
#define SPLITK 4

typedef __attribute__((ext_vector_type(8))) short short8v;   // 8 bf16
typedef __attribute__((ext_vector_type(4))) short short4v;   // 4 bf16
typedef __attribute__((ext_vector_type(4))) float f32x4;     // MFMA acc

static __device__ inline short bf16bits(float f) {
    __hip_bfloat16 h = __float2bfloat16(f);
    return __builtin_bit_cast(short, h);
}
static __device__ inline float bits2f(short s) {
    __hip_bfloat16 h = __builtin_bit_cast(__hip_bfloat16, s);
    return __bfloat162float(h);
}
static __device__ inline short8v cvt8(float4 f0, float4 f1) {
    short8v r;
    r[0] = bf16bits(f0.x); r[1] = bf16bits(f0.y);
    r[2] = bf16bits(f0.z); r[3] = bf16bits(f0.w);
    r[4] = bf16bits(f1.x); r[5] = bf16bits(f1.y);
    r[6] = bf16bits(f1.z); r[7] = bf16bits(f1.w);
    return r;
}
// async global -> LDS, 16 B/lane, linear dest (wave-uniform base + lane*16)
static __device__ inline void glds16(const void* src, void* lds) {
    __builtin_amdgcn_global_load_lds(
        (const __attribute__((address_space(1))) void*)src,
        (__attribute__((address_space(3))) void*)lds, 16, 0, 0);
}
template<int N> static __device__ inline void vmwait() {
    if constexpr (N == 0)  asm volatile("s_waitcnt vmcnt(0)"  ::: "memory");
    else if constexpr (N == 1)  asm volatile("s_waitcnt vmcnt(1)"  ::: "memory");
    else if constexpr (N == 2)  asm volatile("s_waitcnt vmcnt(2)"  ::: "memory");
    else if constexpr (N == 3)  asm volatile("s_waitcnt vmcnt(3)"  ::: "memory");
    else if constexpr (N == 4)  asm volatile("s_waitcnt vmcnt(4)"  ::: "memory");
    else if constexpr (N == 5)  asm volatile("s_waitcnt vmcnt(5)"  ::: "memory");
    else if constexpr (N == 6)  asm volatile("s_waitcnt vmcnt(6)"  ::: "memory");
    else if constexpr (N == 7)  asm volatile("s_waitcnt vmcnt(7)"  ::: "memory");
    else if constexpr (N == 8)  asm volatile("s_waitcnt vmcnt(8)"  ::: "memory");
    else                        asm volatile("s_waitcnt vmcnt(12)" ::: "memory");
}
static __device__ inline void lgkm0_barrier() {
    asm volatile("s_waitcnt lgkmcnt(0)" ::: "memory");
    __builtin_amdgcn_s_barrier();
    __builtin_amdgcn_sched_barrier(0);
}

// Swizzle conventions:
//  SW32  (rows consumed in [*][32]-short LDS tiles): chunk k ^= (row&3)<<3
//  SW128 (rows of >=128 shorts): k ^= (row&7)<<3

// ---------------------------------------------------------------------------
// prep: emb [8192][256] f32 -> embT [256][8192] bf16 SW32 (blocks 0..511)
//       weight packing to bf16 B^T SW32 (blocks 512..1279)
// ---------------------------------------------------------------------------
__global__ __launch_bounds__(256) void prep(
    const float* __restrict__ emb, short* __restrict__ embT,
    const float* __restrict__ Wc, short* __restrict__ Wcb,
    const float* __restrict__ W1, const float* __restrict__ W2,
    short* __restrict__ WcatT)
{
    __shared__ short tile[64][65];
    const int bid = blockIdx.x;
    const int t = threadIdx.x;
    if (bid < 512) {
        const int k0 = (bid & 127) * 64, h0 = (bid >> 7) * 64;
#pragma unroll
        for (int i = 0; i < 16; i++) {
            int idx = t + i * 256;
            int k = idx >> 6, h = idx & 63;
            tile[h][k] = bf16bits(emb[(long)(k0 + k) * 256 + h0 + h]);
        }
        __syncthreads();
#pragma unroll
        for (int i = 0; i < 16; i++) {
            int idx = t + i * 256;
            int h = idx >> 6, k = idx & 63;
            int n = h0 + h;
            int kk = (k0 + k) ^ ((n & 3) << 3);   // SW32
            embT[(long)n * NN + kk] = tile[h][k];
        }
    } else {
        int i = (bid - 512) * 256 + t;
        if (i < 256 * 256) {
            int n = i >> 8, c = i & 255;
            Wcb[n * 256 + (c ^ ((n & 3) << 3))] = bf16bits(Wc[i]);
        }
        if (i < 384 * 512) {
            int n = i >> 9, d = i & 511;
            float v;
            if (n < 128)      v = W1[n * 512 + d];
            else if (n < 256) v = W2[(n - 128) * 1024 + d];
            else              v = W2[(n - 256) * 1024 + 512 + d];
            WcatT[n * 512 + (d ^ ((n & 3) << 3))] = bf16bits(v);
        }
    }
}

// ---------------------------------------------------------------------------
// layer1 = A(f32) @ embT^T -> bf16 partials. BM=128, BN=256, splitK=4.
// A: 2 LDS buffers, SINGLE-stage reg chain (A(t+1) loaded at t-1);
// B: 3-buffer glds ring, depth-2 staging; counted vmcnt, raw barriers.
// 68 KB LDS -> 2 blocks/CU.
// ---------------------------------------------------------------------------
__global__ __launch_bounds__(512, 4) void l1_gemm(
    const float* __restrict__ Af, const short* __restrict__ Bt,
    short* __restrict__ Part)
{
    constexpr int AST = 40;              // padded A row stride (shorts)

    __shared__ short As[2][128 * AST];   // 20 KB
    __shared__ short Bs[3][256 * 32];    // 48 KB

    const int tid = threadIdx.x;
    const int wave = tid >> 6, lane = tid & 63;
    const int wr = wave >> 2, wc = wave & 3;
    const int r16 = lane & 15, kg = lane >> 4;

    const int sk = blockIdx.x & 3, mt = blockIdx.x >> 2;
    const int m0 = mt * 128;
    const int kbeg = sk * 2048;
    constexpr int NIT = 64;              // 2048 / 32

    const int arow = tid >> 2;
    const int akc = (tid & 3) * 8;
    const long arow_g = (long)(m0 + arow) * NN;

    f32x4 acc[4][4] = {};

#define STAGE_B(T, BUF)                                                        \
    {                                                                          \
        const int kt_ = kbeg + (T) * 32;                                       \
        _Pragma("unroll")                                                      \
        for (int c = 0; c < 2; c++) {                                          \
            int chunk = c * 512 + tid;                                         \
            int n_ = chunk >> 2, kc_ = (chunk & 3) * 8;                        \
            glds16(Bt + (long)n_ * NN + kt_ + kc_,                             \
                   &Bs[BUF][(c * 512 + wave * 64) * 8]);                       \
        }                                                                      \
    }
#define LOAD_A(T, F0, F1)                                                      \
    {                                                                          \
        const float* ap_ = Af + arow_g + kbeg + (T) * 32 + akc;                \
        (F0) = *(const float4*)ap_; (F1) = *(const float4*)(ap_ + 4);          \
    }
#define WRITE_A(BUF, F0, F1) { *(short8v*)&As[BUF][arow * AST + akc] = cvt8((F0), (F1)); }

    // prologue: A regs for tiles 0,1; B staged for tiles 0,1
    float4 p0f0, p0f1, c1f0, c1f1;
    LOAD_A(0, p0f0, p0f1);  STAGE_B(0, 0);
    LOAD_A(1, c1f0, c1f1);  STAGE_B(1, 1);
    WRITE_A(0, p0f0, p0f1);              // compiler waits A0 regs
    vmwait<4>();            // drain B0; A1(2)+B1(2) stay in flight
    lgkm0_barrier();

    for (int t = 0; t < NIT; ++t) {
        const int curA = t & 1, nwA = (t + 1) & 1;
        const int curB = t % 3, nsB = (t + 2) % 3;
        float4 nf0, nf1;
        if (t + 2 < NIT) {
            LOAD_A(t + 2, nf0, nf1);
            STAGE_B(t + 2, nsB);
        }

        short8v a[4], b[4];
#pragma unroll
        for (int i = 0; i < 4; i++)
            a[i] = *(const short8v*)&As[curA][(wr * 64 + i * 16 + r16) * AST + kg * 8];
#pragma unroll
        for (int j = 0; j < 4; j++) {
            int n = wc * 64 + j * 16 + r16;
            b[j] = *(const short8v*)&Bs[curB][n * 32 + ((kg * 8) ^ ((n & 3) << 3))];
        }
#pragma unroll
        for (int i = 0; i < 4; i++)
#pragma unroll
            for (int j = 0; j < 4; j++)
                acc[i][j] = __builtin_amdgcn_mfma_f32_16x16x32_bf16(
                    a[i], b[j], acc[i][j], 0, 0, 0);

        if (t + 1 < NIT) {
            WRITE_A(nwA, c1f0, c1f1);    // c1 = A(t+1), loaded at t-1
            if (t + 2 < NIT) vmwait<4>();  // leave A(t+2)+B(t+2) in flight
            else             vmwait<0>();  // drain B(t+1)
            lgkm0_barrier();
        }
        c1f0 = nf0; c1f1 = nf1;          // SINGLE-stage chain (R11 bug fix)
    }
#undef STAGE_B
#undef LOAD_A
#undef WRITE_A

    short* P = Part + (long)sk * NN * HH;
#pragma unroll
    for (int i = 0; i < 4; i++)
#pragma unroll
        for (int j = 0; j < 4; j++) {
            int col = wc * 64 + j * 16 + r16;
#pragma unroll
            for (int r = 0; r < 4; r++) {
                int row = m0 + wr * 64 + i * 16 + kg * 4 + r;
                P[(long)row * HH + col] = bf16bits(acc[i][j][r]);
            }
        }
}

// ---------------------------------------------------------------------------
// layer1 partial reduce (bf16 partials) -> bf16
// ---------------------------------------------------------------------------
__global__ __launch_bounds__(256) void reduceK(
    const short* __restrict__ P, short* __restrict__ out)
{
    const long n = (long)NN * HH;
    long i = ((long)blockIdx.x * 256 + threadIdx.x) * 8;
    if (i >= n) return;
    float acc[8] = {};
#pragma unroll
    for (int k = 0; k < SPLITK; k++) {
        short8v v = *(const short8v*)&P[(long)k * n + i];
#pragma unroll
        for (int j = 0; j < 8; j++) acc[j] += bits2f(v[j]);
    }
    short8v o;
#pragma unroll
    for (int j = 0; j < 8; j++) o[j] = bf16bits(acc[j]);
    *(short8v*)&out[i] = o;
}

// ---------------------------------------------------------------------------
// Small bf16 GEMM template, merged q/a sides + N-tiling for occupancy.
// BM=64, BN=NW*4, 256 threads, depth-3 (4-buffer) pipeline, counted vmcnt.
// ---------------------------------------------------------------------------
template<int NW, int NT, int GATHER, int EPI>
__global__ __launch_bounds__(256) void gemm_small(
    const short* __restrict__ Aq, const short* __restrict__ Aa,
    const short* __restrict__ Bt,
    float* __restrict__ Cfq, float* __restrict__ Cfa,
    short* __restrict__ Cbq, short* __restrict__ Cba,
    short* __restrict__ Ctq, short* __restrict__ Cta,
    const float* __restrict__ bias,
    const int* __restrict__ idxq, const int* __restrict__ idxa,
    int M, int N, int Kd)
{
    constexpr int BM = 64;
    constexpr int BN = NW * 4;
    constexpr int NB = NW / 16;
    constexpr int BCALLS = BN / BM;      // glds per B stage
    constexpr int OPS = 1 + BCALLS;      // vmem ops per stage (A reg-load + B)
    constexpr int AST = 40;

    __shared__ short As[4][BM * AST];
    __shared__ short Bs[4][BN * 32];

    const int tid = threadIdx.x;
    const int wave = tid >> 6, lane = tid & 63;
    const int wc = wave & 3;
    const int r16 = lane & 15, kg = lane >> 4;

    const int bid = blockIdx.x;
    const int side = bid & 1;
    const int nt = (bid >> 1) & (NT - 1);
    const int mt = bid >> (NT == 2 ? 2 : 1);
    const int m0 = mt * BM;
    const int n0 = nt * BN;
    const int niter = Kd / 32;

    const short* Ab = side ? Aa : Aq;
    const int* rowidx = side ? idxa : idxq;

    const int arow = tid >> 2;
    const int akc = (tid & 3) * 8;
    long arow_g;
    { int r = GATHER ? rowidx[m0 + arow] : (m0 + arow); arow_g = (long)r * Kd; }

    f32x4 acc[4][NB] = {};

#define STAGE_B(T, BUF)                                                        \
    {                                                                          \
        const int kt_ = (T) * 32;                                              \
        _Pragma("unroll")                                                      \
        for (int c = 0; c < BCALLS; c++) {                                     \
            int chunk = c * 256 + tid;                                         \
            int n_ = chunk >> 2, kc_ = (chunk & 3) * 8;                        \
            glds16(Bt + (long)(n0 + n_) * Kd + kt_ + kc_,                      \
                   &Bs[BUF][(c * 256 + wave * 64) * 8]);                       \
        }                                                                      \
    }
#define LOAD_A(T, AR)  { (AR) = *(const short8v*)(Ab + arow_g + (T) * 32 + akc); }
#define WRITE_A(BUF, AR) { *(short8v*)&As[BUF][arow * AST + akc] = (AR); }

    // prologue: tiles 0,1,2 (depth-3)
    short8v a0, a1, a2;
    LOAD_A(0, a0);  STAGE_B(0, 0);
    LOAD_A(1, a1);  STAGE_B(1, 1);
    LOAD_A(2, a2);  STAGE_B(2, 2);
    WRITE_A(0, a0);
    vmwait<2 * OPS>();
    lgkm0_barrier();

    for (int t = 0; t < niter; ++t) {
        const int cur = t & 3, nw = (t + 1) & 3, ns = (t + 3) & 3;
        short8v na;
        if (t + 3 < niter) {
            LOAD_A(t + 3, na);
            STAGE_B(t + 3, ns);
        }

        short8v a[4], b[NB];
#pragma unroll
        for (int i = 0; i < 4; i++)
            a[i] = *(const short8v*)&As[cur][(i * 16 + r16) * AST + kg * 8];
#pragma unroll
        for (int j = 0; j < NB; j++) {
            int n = wc * NW + j * 16 + r16;
            b[j] = *(const short8v*)&Bs[cur][n * 32 + ((kg * 8) ^ ((n & 3) << 3))];
        }
#pragma unroll
        for (int i = 0; i < 4; i++)
#pragma unroll
            for (int j = 0; j < NB; j++)
                acc[i][j] = __builtin_amdgcn_mfma_f32_16x16x32_bf16(
                    a[i], b[j], acc[i][j], 0, 0, 0);

        if (t + 1 < niter) {
            WRITE_A(nw, a1);
            if (t + 3 < niter)      vmwait<2 * OPS>();
            else if (t + 2 < niter) vmwait<OPS>();
            else                    vmwait<0>();
            lgkm0_barrier();
        }
        a1 = a2; a2 = na;
    }
#undef STAGE_B
#undef LOAD_A
#undef WRITE_A

    if (EPI == 2) {
        float* Cf = side ? Cfa : Cfq;
#pragma unroll
        for (int i = 0; i < 4; i++)
#pragma unroll
            for (int j = 0; j < NB; j++) {
                int col = n0 + wc * NW + j * 16 + r16;
#pragma unroll
                for (int r = 0; r < 4; r++) {
                    int row = m0 + i * 16 + kg * 4 + r;
                    Cf[(long)row * N + col] = acc[i][j][r];
                }
            }
    } else {   // EPI == 1: gram
        short* Cb = side ? Cba : Cbq;
        short* Ct = side ? Cta : Ctq;
#pragma unroll
        for (int i = 0; i < 4; i++)
#pragma unroll
            for (int j = 0; j < NB; j++) {
                int col = n0 + wc * NW + j * 16 + r16;
                float bv = bias[col];
                float vr[4];
#pragma unroll
                for (int r = 0; r < 4; r++)
                    vr[r] = fmaxf(acc[i][j][r] + bv, 0.f);
                int rbase = m0 + i * 16 + kg * 4;
                int bb = rbase >> 7;
                int lbase = rbase & 127;
#pragma unroll
                for (int r = 0; r < 4; r++) {
                    int grow = rbase + r;
                    Cb[(long)grow * 256 + (col ^ ((grow & 7) << 3))] = bf16bits(vr[r]);
                }
                short4v t4;
#pragma unroll
                for (int r = 0; r < 4; r++) t4[r] = bf16bits(vr[r]);
                int lsw = lbase ^ ((col & 7) << 3);
                *(short4v*)&Ct[(long)bb * (256 * 128) + col * 128 + lsw] = t4;
            }
    }
}

// ---------------------------------------------------------------------------
// qkT: per (batch, q-half): s[q][k] = Qm[b,q,:] . Am[b,k,:]  (bf16 MFMA)
// grid = 2*BB. Q-half 64 rows (32 KB) + Am full (64 KB) in LDS.
// ---------------------------------------------------------------------------
__global__ __launch_bounds__(256) void qkT(
    const short* __restrict__ Qb16, const short* __restrict__ Ab16,
    float* __restrict__ s)
{
    __shared__ short Q[64 * 256];     // 32 KB
    __shared__ short Am[128 * 256];   // 64 KB
    const int b = blockIdx.x >> 1;
    const int qh = blockIdx.x & 1;
    const int tid = threadIdx.x, wave = tid >> 6, lane = tid & 63;
    const int r16 = lane & 15, kg = lane >> 4;
    const long boff = (long)b * 128 * 256;
    const long qoff = boff + (long)qh * 64 * 256;

#pragma unroll
    for (int c = 0; c < 8; c++)
        glds16(Qb16 + qoff + ((long)c * 256 + tid) * 8, &Q[(c * 256 + wave * 64) * 8]);
#pragma unroll
    for (int c = 0; c < 16; c++)
        glds16(Ab16 + boff + ((long)c * 256 + tid) * 8, &Am[(c * 256 + wave * 64) * 8]);
    __syncthreads();

    f32x4 acc[8] = {};
    const int q0 = wave * 16;
#pragma unroll
    for (int ks = 0; ks < 8; ks++) {
        short8v a;
        {
            int q = q0 + r16;
            a = *(const short8v*)&Q[q * 256 + ((ks * 32 + kg * 8) ^ ((q & 7) << 3))];
        }
#pragma unroll
        for (int j = 0; j < 8; j++) {
            int n = j * 16 + r16;
            short8v bf = *(const short8v*)&Am[n * 256 + ((ks * 32 + kg * 8) ^ ((n & 7) << 3))];
            acc[j] = __builtin_amdgcn_mfma_f32_16x16x32_bf16(a, bf, acc[j], 0, 0, 0);
        }
    }

    float* sp = s + (long)b * 16384 + (long)qh * 64 * 128;
#pragma unroll
    for (int j = 0; j < 8; j++)
#pragma unroll
        for (int r = 0; r < 4; r++) {
            int q = q0 + kg * 4 + r;
            int k = j * 16 + r16;
            sp[q * 128 + k] = acc[j][r];
        }
}

// ---------------------------------------------------------------------------
// attn_pv split (runtime side + 64-row half): softmax of s rows (side 0) /
// cols (side 1) -> P [64][128], E = P @ XT^T, fused t-features bf16.
// grid = 4*BB: b = bid>>2, side = (bid>>1)&1, half = bid&1.
// ---------------------------------------------------------------------------
__global__ __launch_bounds__(256) void attn_pv(
    const float* __restrict__ s,
    const short* __restrict__ AT, const short* __restrict__ QT,
    const short* __restrict__ Qb16, const short* __restrict__ Ab16,
    short* __restrict__ t_q, short* __restrict__ t_a)
{
    __shared__ short XL[256 * 128];   // 64 KB  (XT full, staged concurrently)
    __shared__ float sm[64 * 128];    // 32 KB  (s half)
    __shared__ short P[64 * 128];     // 16 KB
    const int b = blockIdx.x >> 2;
    const int side = (blockIdx.x >> 1) & 1;
    const int h = blockIdx.x & 1;
    const int tid = threadIdx.x, wave = tid >> 6, lane = tid & 63;
    const int r16 = lane & 15, kg = lane >> 4;

    const short* XT   = side ? QT : AT;
    const short* Xrow = side ? Ab16 : Qb16;
    short* tout       = side ? t_a : t_q;

    // stage XT full (64 KB)
#pragma unroll
    for (int c = 0; c < 16; c++)
        glds16(XT + (long)b * 32768 + ((long)c * 256 + tid) * 8,
               &XL[(c * 256 + wave * 64) * 8]);
    // stage s half (32 KB)
    if (side == 0) {
        // rows [h*64, h*64+64) full width -> sm[r][k] = s[b][h*64+r][k]
#pragma unroll
        for (int c = 0; c < 8; c++)
            glds16(s + (long)b * 16384 + (long)h * 8192 + ((long)c * 256 + tid) * 4,
                   &sm[(c * 256 + wave * 64) * 4]);
    } else {
        // cols [h*64, h*64+64) all q -> sm[q][kl] = s[b][q][h*64+kl]  ([128][64])
#pragma unroll
        for (int c = 0; c < 8; c++) {
            int idx = c * 256 + tid;          // 16-B unit
            int q = idx >> 4, off = (idx & 15) * 4;
            glds16(s + (long)b * 16384 + (long)q * 128 + h * 64 + off,
                   &sm[(c * 256 + wave * 64) * 4]);
        }
    }
    __syncthreads();

    {   // softmax: 4 threads per row/col, shfl_xor(1,2) combine
        const int r = tid >> 2;          // local row (side0) / local col (side1)
        const int qt = tid & 3;
        float mx = -1e30f;
#pragma unroll 8
        for (int i = 0; i < 32; i++) {
            int k = qt * 32 + ((i + r) & 31);
            float v = (side == 0) ? sm[r * 128 + k] : sm[k * 64 + r];
            mx = fmaxf(mx, v);
        }
        mx = fmaxf(mx, __shfl_xor(mx, 1));
        mx = fmaxf(mx, __shfl_xor(mx, 2));
        float sum = 0.f;
#pragma unroll 8
        for (int i = 0; i < 32; i++) {
            int k = qt * 32 + ((i + r) & 31);
            float v = (side == 0) ? sm[r * 128 + k] : sm[k * 64 + r];
            sum += __expf(v - mx);
        }
        sum += __shfl_xor(sum, 1);
        sum += __shfl_xor(sum, 2);
        float inv = 1.f / sum;
#pragma unroll 8
        for (int i = 0; i < 32; i++) {
            int k = qt * 32 + ((i + r) & 31);
            float v = (side == 0) ? sm[r * 128 + k] : sm[k * 64 + r];
            P[r * 128 + (k ^ ((r & 7) << 3))] = bf16bits(__expf(v - mx) * inv);
        }
    }
    __syncthreads();

    f32x4 acc[4][4] = {};
#pragma unroll
    for (int ks = 0; ks < 4; ks++) {
        short8v a[4], bf[4];
#pragma unroll
        for (int i = 0; i < 4; i++) {
            int row = i * 16 + r16;
            a[i] = *(const short8v*)&P[row * 128 + ((ks * 32 + kg * 8) ^ ((row & 7) << 3))];
        }
#pragma unroll
        for (int j = 0; j < 4; j++) {
            int hh = wave * 64 + j * 16 + r16;
            bf[j] = *(const short8v*)&XL[hh * 128 + ((ks * 32 + kg * 8) ^ ((hh & 7) << 3))];
        }
#pragma unroll
        for (int i = 0; i < 4; i++)
#pragma unroll
            for (int j = 0; j < 4; j++)
                acc[i][j] = __builtin_amdgcn_mfma_f32_16x16x32_bf16(
                    a[i], bf[j], acc[i][j], 0, 0, 0);
    }

    short* tp = tout + (long)b * 128 * 512 + (long)h * 64 * 512;
    const short* xr = Xrow + (long)b * 128 * 256 + (long)h * 64 * 256;
#pragma unroll
    for (int i = 0; i < 4; i++)
#pragma unroll
        for (int j = 0; j < 4; j++) {
            int col = wave * 64 + j * 16 + r16;
#pragma unroll
            for (int r = 0; r < 4; r++) {
                int row = i * 16 + kg * 4 + r;   // local 0..63
                float E = acc[i][j][r];
                float x = bits2f(xr[row * 256 + (col ^ ((row & 7) << 3))]);
                float d = x - E;
                tp[(long)row * 512 + col] = bf16bits(d * d);
                tp[(long)row * 512 + 256 + col] = bf16bits(x * E);
            }
        }
}

// ---------------------------------------------------------------------------
// pool + final fused: 512 threads, one (side,k) pair per thread.
// ---------------------------------------------------------------------------
__global__ __launch_bounds__(512) void pool_final(
    const float* __restrict__ u_q, const float* __restrict__ u_a,
    const float* __restrict__ b1, const float* __restrict__ b2,
    const float* __restrict__ Wd, const float* __restrict__ bd,
    float* __restrict__ out)
{
    __shared__ float re[512];
    const int b = blockIdx.x;
    const int t = threadIdx.x;
    const int side = t >> 8;
    const int kk = t & 255;
    const float* uu = side ? u_a : u_q;
    if (kk < 128) {
        int k = kk;
        float bias = b1[k];
        float mx = -1e30f;
        for (int l = 0; l < 128; l++) {
            float v = uu[((long)b * 128 + l) * 384 + k] + bias;
            mx = fmaxf(mx, v);
        }
        re[side * 256 + k] = fmaxf(mx, 0.f);
    } else {
        int k = kk - 128;
        float bias = b2[k];
        float mx = -1e30f;
        for (int l = 0; l < 127; l++) {
            float v = uu[((long)b * 128 + l) * 384 + 128 + k]
                    + uu[((long)b * 128 + l + 1) * 384 + 256 + k] + bias;
            mx = fmaxf(mx, v);
        }
        re[side * 256 + 128 + k] = fmaxf(mx, 0.f);
    }
    __syncthreads();
    if (t < 64) {
        float p0 = 0.f, p1 = 0.f;
        for (int d = t; d < 512; d += 64) {
            float r = re[d];
            p0 = fmaf(r, Wd[d], p0);
            p1 = fmaf(r, Wd[512 + d], p1);
        }
#pragma unroll
        for (int off = 32; off; off >>= 1) {
            p0 += __shfl_xor(p0, off);
            p1 += __shfl_xor(p1, off);
        }
        if (t == 0) {
            float l0 = p0 + bd[0], l1 = p1 + bd[1];
            float m = fmaxf(l0, l1);
            float lse = m + logf(expf(l0 - m) + expf(l1 - m));
            out[b * 2 + 0] = l0 - lse;
            out[b * 2 + 1] = l1 - lse;
        }
    }
}

// ---------------------------------------------------------------------------
extern "C" void kernel_launch(void* const* d_in, const int* in_sizes, int n_in,
                              void* d_out, int out_size, void* d_ws, size_t ws_size,
                              hipStream_t stream)
{
    const float* A    = (const float*)d_in[0];
    const float* emb  = (const float*)d_in[1];
    const float* Wc   = (const float*)d_in[2];
    const float* bc   = (const float*)d_in[3];
    const float* W1   = (const float*)d_in[4];
    const float* b1   = (const float*)d_in[5];
    const float* W2   = (const float*)d_in[6];
    const float* b2   = (const float*)d_in[7];
    const float* Wd   = (const float*)d_in[8];
    const float* bd   = (const float*)d_in[9];
    const int* q_idx  = (const int*)d_in[10];
    const int* a_idx  = (const int*)d_in[11];
    float* out = (float*)d_out;
    float* ws  = (float*)d_ws;

    // workspace layout (float units)
    const long SZ_L1 = (long)NN * HH;                 // 2,097,152
    float* p      = ws;
    short* Part   = (short*)p;          p += (long)SPLITK * SZ_L1 / 2;  // bf16
    short* l1b    = (short*)p;          p += SZ_L1 / 2 + 1024;   // bf16 [8192][256]
    short* Wcb    = (short*)p;          p += 32768 + 1024;       // bf16 [256][256] SW32
    short* WcatT  = (short*)p;          p += 98304 + 1024;       // bf16 [384][512] SW32
    short* embT   = (short*)p;          p += SZ_L1 / 2 + 1024;   // bf16 [256][8192] SW32
    short* Qb16   = (short*)p;          p += SZ_L1 / 2 + 1024;   // bf16 [8192][256] SW128
    short* Ab16   = (short*)p;          p += SZ_L1 / 2 + 1024;
    short* QT     = (short*)p;          p += SZ_L1 / 2 + 1024;   // bf16 [64][256][128] SW128
    short* AT     = (short*)p;          p += SZ_L1 / 2 + 1024;
    float* s      = p;                  p += (long)BB * LL * LL; // f32 [64][128][128]
    short* t_q    = (short*)p;          p += SZ_L1 + 1024;       // bf16 [8192][512]
    short* t_a    = (short*)p;          p += SZ_L1 + 1024;
    float* u_q    = p;                  p += (long)BB * LL * 384;
    float* u_a    = p;                  p += (long)BB * LL * 384;

    // 1. weight packing + emb transpose
    prep<<<1280, 256, 0, stream>>>(emb, embT, Wc, Wcb, W1, W2, WcatT);

    // 2. layer1: splitK=4, 256 blocks, 68 KB LDS -> 2 blocks/CU
    l1_gemm<<<256, 512, 0, stream>>>(A, embT, Part);
    reduceK<<<(int)(SZ_L1 / 8 / 256), 256, 0, stream>>>(Part, l1b);

    // 3. gram merged q+a: BN=128 x 2 n-tiles x 2 sides = 512 blocks
    gemm_small<32, 2, 1, 1><<<512, 256, 0, stream>>>(
        l1b, l1b, Wcb, nullptr, nullptr, Qb16, Ab16, QT, AT, bc,
        q_idx, a_idx, BB * LL, HH, HH);

    // 4. attention: qkT split by q-half (128 blocks), attn_pv quarter (256)
    qkT<<<2 * BB, 256, 0, stream>>>(Qb16, Ab16, s);
    attn_pv<<<4 * BB, 256, 0, stream>>>(s, AT, QT, Qb16, Ab16, t_q, t_a);

    // 5. encoder merged q+a: BN=192 x 2 n-tiles x 2 sides = 512 blocks
    gemm_small<48, 2, 0, 2><<<512, 256, 0, stream>>>(
        t_q, t_a, WcatT, u_q, u_a, nullptr, nullptr, nullptr, nullptr, nullptr,
        nullptr, nullptr, BB * LL, 384, 512);

    // 6. pool + final
    pool_final<<<BB, 512, 0, stream>>>(u_q, u_a, b1, b2, Wd, bd, out);
}